// Round 2
// baseline (1106.766 us; speedup 1.0000x reference)
//
#include <hip/hip_runtime.h>
#include <hip/hip_bf16.h>

typedef __hip_bfloat16 BF16;

// dual-dtype scalar load: bf==1 -> bf16, bf==0 -> f32
__device__ __forceinline__ float ldv(const void* p, size_t i, int bf){
    return bf ? __bfloat162float(((const BF16*)p)[i]) : ((const float*)p)[i];
}

// Decide whether raw buffers are bf16 or f32 by scanning x interpreted as bf16.
// True-bf16 N(0,1) data: no wild exponents. f32 data read as bf16: ~73% of the
// low-half words have wild exponents. flag=1 -> bf16, flag=0 -> f32.
__global__ __launch_bounds__(256) void detect_k(const void* __restrict__ x, int* __restrict__ flag){
    __shared__ int cnt;
    if (threadIdx.x == 0) cnt = 0;
    __syncthreads();
    int local = 0;
    for (int i = threadIdx.x; i < 4096; i += 256) {
        float v = __bfloat162float(((const BF16*)x)[i]);
        float a = fabsf(v);
        if (!(a == 0.f || (a >= 1e-10f && a <= 1e10f))) local++;  // NaN/Inf land here too
    }
    atomicAdd(&cnt, local);
    __syncthreads();
    if (threadIdx.x == 0) *flag = (cnt < 64) ? 1 : 0;
}

// C = act(A @ W + bias); A: M x K (ws f32, or raw input if a_input), W: K x N (raw), C: M x N f32
// 64x64 tile, 256 threads, 4x4/thread, BK=16
__global__ __launch_bounds__(256) void gemm_k(const void* __restrict__ A,
    const void* __restrict__ W, const void* __restrict__ bias,
    float* __restrict__ C, int M, int K, int N,
    int a_input, int relu, const int* __restrict__ dflag)
{
    int bf  = *dflag;
    int abf = a_input ? bf : 0;
    __shared__ float As[64][17];
    __shared__ float Bs[16][65];
    int tid = threadIdx.x;
    int tx = tid & 15, ty = tid >> 4;
    int row0 = blockIdx.x * 64, col0 = blockIdx.y * 64;
    float acc[4][4];
    #pragma unroll
    for (int r = 0; r < 4; r++)
        #pragma unroll
        for (int c = 0; c < 4; c++) acc[r][c] = 0.f;

    for (int k0 = 0; k0 < K; k0 += 16) {
        #pragma unroll
        for (int i = 0; i < 4; i++) {
            int e = tid + i * 256;
            int r = e >> 4, kk = e & 15;
            int gr = row0 + r;
            As[r][kk] = (gr < M) ? ldv(A, (size_t)gr * K + k0 + kk, abf) : 0.f;
        }
        #pragma unroll
        for (int i = 0; i < 4; i++) {
            int e = tid + i * 256;
            int kk = e >> 6, c = e & 63;
            Bs[kk][c] = ldv(W, (size_t)(k0 + kk) * N + col0 + c, bf);
        }
        __syncthreads();
        #pragma unroll
        for (int kk = 0; kk < 16; kk++) {
            float a[4], b[4];
            #pragma unroll
            for (int r = 0; r < 4; r++) a[r] = As[ty * 4 + r][kk];
            #pragma unroll
            for (int c = 0; c < 4; c++) b[c] = Bs[kk][tx * 4 + c];
            #pragma unroll
            for (int r = 0; r < 4; r++)
                #pragma unroll
                for (int c = 0; c < 4; c++)
                    acc[r][c] += a[r] * b[c];
        }
        __syncthreads();
    }
    #pragma unroll
    for (int r = 0; r < 4; r++) {
        int gr = row0 + ty * 4 + r;
        if (gr >= M) continue;
        #pragma unroll
        for (int c = 0; c < 4; c++) {
            int gc = col0 + tx * 4 + c;
            float v = acc[r][c];
            if (bias) v += ldv(bias, gc, bf);
            if (relu) v = fmaxf(v, 0.f);
            C[(size_t)gr * N + gc] = v;
        }
    }
}

// Level-1 fused masked attention per (b,n,d) over 64x64 (all ws f32)
__global__ __launch_bounds__(256) void attn1_k(const float* __restrict__ A1,
    const float* __restrict__ B2, const float* __restrict__ X,
    float* __restrict__ H, int fw)
{
    __shared__ float sB[64][64];
    __shared__ float sX[64][64];
    int dl = threadIdx.x & 63, il = threadIdx.x >> 6;
    int i = blockIdx.x * 4 + il;
    int d0 = blockIdx.y * 64;
    int bn = blockIdx.z;
    size_t rowbase = (size_t)bn * 64;
    for (int e = threadIdx.x; e < 4096; e += 256) {
        int j = e >> 6, dd = e & 63;
        sB[j][dd] = B2[(rowbase + j) * 256 + d0 + dd];
        sX[j][dd] = X[(rowbase + j) * 256 + d0 + dd];
    }
    __syncthreads();
    float Av = A1[(rowbase + i) * 256 + d0 + dl];
    int js = fw ? (i + 1) : 0;
    int je = fw ? 64 : i;
    float den = 0.f, num = 0.f;
    for (int j = js; j < je; j++) {
        float z = (Av + sB[j][dl]) * 0.2f;
        float e2 = __expf(2.f * z);
        float t = 1.f - 2.f / (e2 + 1.f);
        float w = __expf(5.f * t);            // scores in [-5,5]
        den += w;
        num += w * sX[j][dl];
    }
    float out = (je > js) ? (num / den) : 0.f;
    H[(rowbase + i) * 256 + d0 + dl] = out;
}

// s2t pool: softmax over r of logits, weighted sum of H -> V (B*N, D)
__global__ __launch_bounds__(256) void s2t_k(const float* __restrict__ L,
    const float* __restrict__ Hh, float* __restrict__ V)
{
    int bn = blockIdx.x, d = threadIdx.x;
    float m = -1e30f, den = 0.f, num = 0.f;
    for (int r = 0; r < 64; r++) {
        size_t idx = ((size_t)bn * 64 + r) * 256 + d;
        float l = L[idx], h = Hh[idx];
        if (l > m) {
            float sc = __expf(m - l);
            den *= sc; num *= sc; m = l;
        }
        float w = __expf(l - m);
        den += w; num += w * h;
    }
    V[(size_t)bn * 256 + d] = num / den;
}

// Level-2 attention, only row i=0 consumed (idx == all zeros). bw row0 -> 0.
__global__ __launch_bounds__(256) void attn2_k(const float* __restrict__ vW1,
    const float* __restrict__ vW2b, const float* __restrict__ V,
    float* __restrict__ O0, int fw)
{
    int b = blockIdx.x, d = threadIdx.x;
    float out = 0.f;
    if (fw) {
        float q = vW1[((size_t)b * 16) * 256 + d];
        float den = 0.f, num = 0.f;
        for (int j = 1; j < 16; j++) {
            float z = (q + vW2b[((size_t)b * 16 + j) * 256 + d]) * 0.2f;
            float e2 = __expf(2.f * z);
            float t = 1.f - 2.f / (e2 + 1.f);
            float w = __expf(5.f * t);
            den += w; num += w * V[((size_t)b * 16 + j) * 256 + d];
        }
        out = num / den;
    }
    O0[b * 256 + d] = out;
}

// e0 = G*o0 + (1-G)*v0, G = sigmoid(o0@gW1 + v0@gW2 + gb), row n=0 only
__global__ __launch_bounds__(256) void gate_k(const float* __restrict__ O0,
    const float* __restrict__ V, const void* __restrict__ gW1,
    const void* __restrict__ gW2, const void* __restrict__ gb,
    float* __restrict__ E0, const int* __restrict__ dflag)
{
    int bf = *dflag;
    __shared__ float so[256], sv[256];
    int b = blockIdx.x, d = threadIdx.x;
    so[d] = O0[b * 256 + d];
    sv[d] = V[((size_t)b * 16) * 256 + d];
    __syncthreads();
    float acc = ldv(gb, d, bf);
    for (int k = 0; k < 256; k++)
        acc += so[k] * ldv(gW1, (size_t)k * 256 + d, bf)
             + sv[k] * ldv(gW2, (size_t)k * 256 + d, bf);
    float G = 1.f / (1.f + __expf(-acc));
    E0[b * 256 + d] = G * so[d] + (1.f - G) * sv[d];
}

// fusion over cat=[xf,hf,E0] (768) -> out slice (B,16,:) at channel offset p*256
__global__ __launch_bounds__(256) void fusion_k(const float* __restrict__ IN,
    const float* __restrict__ H, const float* __restrict__ E0,
    const void* __restrict__ fW1, const void* __restrict__ fb1,
    const void* __restrict__ fW2, const void* __restrict__ fb2,
    void* __restrict__ out, int p, const int* __restrict__ dflag)
{
    int bf = *dflag;
    __shared__ float cat[768];
    int bt = blockIdx.x, b = bt >> 4, t = bt & 15, d = threadIdx.x;
    size_t xrow = ((size_t)b * 1024 + t) * 256;  // (b, n=0, r=t) row of (B, N*R, D)
    cat[d]       = IN[xrow + d];
    cat[256 + d] = H[xrow + d];
    cat[512 + d] = E0[b * 256 + d];
    __syncthreads();
    float a1 = ldv(fb1, d, bf), a2 = ldv(fb2, d, bf);
    for (int k = 0; k < 768; k++) {
        float cv = cat[k];
        a1 += cv * ldv(fW1, (size_t)k * 256 + d, bf);
        a2 += cv * ldv(fW2, (size_t)k * 256 + d, bf);
    }
    float fus = fmaxf(a1, 0.f);
    float Gf = 1.f / (1.f + __expf(-a2));
    float xfv = cat[d];
    float u = Gf * fus + (1.f - Gf) * xfv;
    size_t oi = ((size_t)(b * 16 + t)) * 512 + (size_t)p * 256 + d;
    if (bf) ((BF16*)out)[oi] = __float2bfloat16(u);
    else    ((float*)out)[oi] = u;
}

extern "C" void kernel_launch(void* const* d_in, const int* in_sizes, int n_in,
                              void* d_out, int out_size, void* d_ws, size_t ws_size,
                              hipStream_t stream)
{
    const void* x = d_in[0];
    int* flag = (int*)d_ws;
    float* w = (float*)d_ws + 64;   // keep flag in its own cacheline region
    float* buf_in  = w; w += 1048576;  // (B,N,R,D) post-fc
    float* buf_A1  = w; w += 1048576;  // xW1 / relu-t1
    float* buf_A2  = w; w += 1048576;  // xW2+mb / logits
    float* buf_h   = w; w += 1048576;  // h
    float* buf_v   = w; w += 16384;    // (B*N, D)
    float* buf_vW1 = w; w += 16384;
    float* buf_vW2 = w; w += 16384;
    float* buf_o0  = w; w += 1024;     // (B, D)
    float* buf_e0  = w; w += 1024;

    detect_k<<<1, 256, 0, stream>>>(x, flag);

    for (int p = 0; p < 2; p++) {
        int base = 1 + p * 16;
        const void* fcW   = d_in[base + 0];
        const void* fcb   = d_in[base + 1];
        const void* mW1   = d_in[base + 2];
        const void* mW2   = d_in[base + 3];
        const void* mb    = d_in[base + 4];
        const void* s2tW1 = d_in[base + 5];
        const void* s2tb1 = d_in[base + 6];
        const void* s2tW  = d_in[base + 7];
        const void* s2tb  = d_in[base + 8];
        const void* gW1   = d_in[base + 9];
        const void* gW2   = d_in[base + 10];
        const void* gb    = d_in[base + 11];
        const void* fW1   = d_in[base + 12];
        const void* fb1   = d_in[base + 13];
        const void* fW2   = d_in[base + 14];
        const void* fb2   = d_in[base + 15];
        int fw = (p == 0);

        dim3 gg(64, 4);  // M=4096, N=256
        gemm_k<<<gg, 256, 0, stream>>>(x, fcW, fcb, buf_in, 4096, 256, 256, 1, 1, flag);
        gemm_k<<<gg, 256, 0, stream>>>(buf_in, mW1, nullptr, buf_A1, 4096, 256, 256, 0, 0, flag);
        gemm_k<<<gg, 256, 0, stream>>>(buf_in, mW2, mb, buf_A2, 4096, 256, 256, 0, 0, flag);
        attn1_k<<<dim3(16, 4, 64), 256, 0, stream>>>(buf_A1, buf_A2, buf_in, buf_h, fw);
        gemm_k<<<gg, 256, 0, stream>>>(buf_h, s2tW1, s2tb1, buf_A1, 4096, 256, 256, 0, 1, flag);
        gemm_k<<<gg, 256, 0, stream>>>(buf_A1, s2tW, s2tb, buf_A2, 4096, 256, 256, 0, 0, flag);
        s2t_k<<<64, 256, 0, stream>>>(buf_A2, buf_h, buf_v);
        dim3 gs(1, 4);   // M=64
        gemm_k<<<gs, 256, 0, stream>>>(buf_v, mW1, nullptr, buf_vW1, 64, 256, 256, 0, 0, flag);
        gemm_k<<<gs, 256, 0, stream>>>(buf_v, mW2, mb, buf_vW2, 64, 256, 256, 0, 0, flag);
        attn2_k<<<4, 256, 0, stream>>>(buf_vW1, buf_vW2, buf_v, buf_o0, fw);
        gate_k<<<4, 256, 0, stream>>>(buf_o0, buf_v, gW1, gW2, gb, buf_e0, flag);
        fusion_k<<<64, 256, 0, stream>>>(buf_in, buf_h, buf_e0, fW1, fb1, fW2, fb2, d_out, p, flag);
    }
}

// Round 4
// 366.996 us; speedup vs baseline: 3.0157x; 3.0157x over previous
//
#include <hip/hip_runtime.h>
#include <hip/hip_bf16.h>

typedef __hip_bfloat16 BF16;
typedef __attribute__((ext_vector_type(8))) short short8;
typedef __attribute__((ext_vector_type(4))) float f32x4;

__device__ __forceinline__ short f2bs(float f){
    BF16 h = __float2bfloat16(f);
    return *(short*)&h;
}
__device__ __forceinline__ float bs2f(short s){
    BF16 h = *(BF16*)&s;
    return __bfloat162float(h);
}

// ---------- prep: transpose+split 10 f32 weight mats (256x256) to n-major bf16 hi/lo ----------
struct SrcPack { const float* s[10]; };

__global__ __launch_bounds__(256) void transpose_k(SrcPack p, short* __restrict__ Oh,
                                                   short* __restrict__ Ol)
{
    __shared__ float s[64][65];
    const float* W = p.s[blockIdx.y];
    short* oh = Oh + (size_t)blockIdx.y * 65536;
    short* ol = Ol + (size_t)blockIdx.y * 65536;
    int tr = (blockIdx.x >> 2) * 64, tc = (blockIdx.x & 3) * 64;
    #pragma unroll
    for (int i = 0; i < 16; i++) {
        int e = threadIdx.x + i * 256;
        int r = e >> 6, c = e & 63;
        s[c][r] = W[(size_t)(tr + r) * 256 + tc + c];
    }
    __syncthreads();
    #pragma unroll
    for (int i = 0; i < 16; i++) {
        int e = threadIdx.x + i * 256;
        int c2 = e >> 6, r2 = e & 63;
        float v = s[c2][r2];
        short hi = f2bs(v);
        short lo = f2bs(v - bs2f(hi));
        size_t oi = (size_t)(tc + c2) * 256 + tr + r2;
        oh[oi] = hi;
        ol[oi] = lo;
    }
}

// ---------- MFMA GEMM with split-bf16 precision ----------
// C[row0..+63][col0..+63] = act(A @ W + bias); A: Mx256 f32 (ASPLIT=1, hi/lo split)
// or Mx256 bf16-shorts (ASPLIT=0). W pre-transposed n-major hi/lo. C: f32 or bf16 (OBF).
// 4 waves; wave w does rows w*16..+15 x 64 cols. K in 4 chunks of 64.
template<int ASPLIT, int OBF, int RELU>
__device__ __forceinline__ void gemm_body(const void* __restrict__ Av,
    const short* __restrict__ Wh, const short* __restrict__ Wl,
    const float* __restrict__ bias, void* __restrict__ Cv, int row0, int col0)
{
    constexpr int LDK = 72;  // shorts; 36 words/row -> 4m bank pattern, conflict-benign
    __shared__ short sAh[64 * LDK];
    __shared__ short sAl[ASPLIT ? 64 * LDK : 8];
    __shared__ short sBh[64 * LDK];
    __shared__ short sBl[64 * LDK];
    int tid = threadIdx.x;
    int w = tid >> 6, l = tid & 63;
    int m = l & 15, q = l >> 4;
    int sr = w * 16 + m;

    f32x4 acc[4];
    #pragma unroll
    for (int cf = 0; cf < 4; cf++) acc[cf] = (f32x4)(0.f);

    for (int kh = 0; kh < 4; kh++) {
        int kbase = kh * 64;
        #pragma unroll
        for (int i = 0; i < 2; i++) {
            int kl = q * 8 + 32 * i;
            if (ASPLIT) {
                const float* src = (const float*)Av + (size_t)(row0 + sr) * 256 + kbase + kl;
                short8 vh, vl;
                #pragma unroll
                for (int j = 0; j < 8; j++) {
                    float v = src[j];
                    vh[j] = f2bs(v);
                    vl[j] = f2bs(v - bs2f(vh[j]));
                }
                *(short8*)&sAh[sr * LDK + kl] = vh;
                *(short8*)&sAl[sr * LDK + kl] = vl;
            } else {
                short8 va = *(const short8*)((const short*)Av + (size_t)(row0 + sr) * 256 + kbase + kl);
                *(short8*)&sAh[sr * LDK + kl] = va;
            }
            *(short8*)&sBh[sr * LDK + kl] = *(const short8*)(Wh + (size_t)(col0 + sr) * 256 + kbase + kl);
            *(short8*)&sBl[sr * LDK + kl] = *(const short8*)(Wl + (size_t)(col0 + sr) * 256 + kbase + kl);
        }
        __syncthreads();
        #pragma unroll
        for (int ch = 0; ch < 2; ch++) {
            int k = ch * 32 + q * 8;
            short8 ah = *(const short8*)&sAh[(w * 16 + m) * LDK + k];
            short8 al = ASPLIT ? *(const short8*)&sAl[(w * 16 + m) * LDK + k] : ah;
            #pragma unroll
            for (int cf = 0; cf < 4; cf++) {
                short8 bh = *(const short8*)&sBh[(cf * 16 + m) * LDK + k];
                short8 bl = *(const short8*)&sBl[(cf * 16 + m) * LDK + k];
                acc[cf] = __builtin_amdgcn_mfma_f32_16x16x32_bf16(ah, bh, acc[cf], 0, 0, 0);
                acc[cf] = __builtin_amdgcn_mfma_f32_16x16x32_bf16(ah, bl, acc[cf], 0, 0, 0);
                if (ASPLIT)
                    acc[cf] = __builtin_amdgcn_mfma_f32_16x16x32_bf16(al, bh, acc[cf], 0, 0, 0);
            }
        }
        __syncthreads();
    }
    // C/D layout: col = lane&15, row = (lane>>4)*4 + reg (m89-verified)
    #pragma unroll
    for (int cf = 0; cf < 4; cf++) {
        int col = col0 + cf * 16 + m;
        float bv = bias ? bias[col] : 0.f;
        #pragma unroll
        for (int r = 0; r < 4; r++) {
            int row = row0 + w * 16 + q * 4 + r;
            float v = acc[cf][r] + bv;
            if (RELU) v = fmaxf(v, 0.f);
            if (OBF) ((short*)Cv)[(size_t)row * 256 + col] = f2bs(v);
            else     ((float*)Cv)[(size_t)row * 256 + col] = v;
        }
    }
}

template<int ASPLIT, int OBF, int RELU>
__global__ __launch_bounds__(256) void gemm_k(const void* __restrict__ Av,
    const short* __restrict__ Wh, const short* __restrict__ Wl,
    const float* __restrict__ bias, void* __restrict__ Cv)
{
    gemm_body<ASPLIT, OBF, RELU>(Av, Wh, Wl, bias, Cv, blockIdx.x * 64, blockIdx.y * 64);
}

// fused dual GEMM (shared A): C1 = A@W1 ; C2 = A@W2 + b2 (grid.y 0..7)
template<int OBF>
__global__ __launch_bounds__(256) void gemm2_k(const float* __restrict__ A,
    const short* __restrict__ W1h, const short* __restrict__ W1l,
    const short* __restrict__ W2h, const short* __restrict__ W2l,
    const float* __restrict__ bias2, void* __restrict__ C1, void* __restrict__ C2)
{
    int y = blockIdx.y;
    const short* Wh = (y < 4) ? W1h : W2h;
    const short* Wl = (y < 4) ? W1l : W2l;
    void* C = (y < 4) ? C1 : C2;
    const float* bias = (y < 4) ? nullptr : bias2;
    gemm_body<1, OBF, 0>(A, Wh, Wl, bias, C, blockIdx.x * 64, (y & 3) * 64);
}

// ---------- level-1 fused masked attention per (b,n,d) over 64x64 ----------
// A1, A2 bf16 planes; X f32.
__global__ __launch_bounds__(256) void attn1_k(const short* __restrict__ A1,
    const short* __restrict__ A2, const float* __restrict__ X,
    float* __restrict__ H, int fw)
{
    __shared__ float sB[64][64];
    __shared__ float sX[64][64];
    int dl = threadIdx.x & 63, il = threadIdx.x >> 6;
    int i = blockIdx.x * 4 + il;
    int d0 = blockIdx.y * 64;
    int bn = blockIdx.z;
    size_t rowbase = (size_t)bn * 64;
    for (int e = threadIdx.x; e < 512; e += 256) {
        int j = e >> 3, d8 = (e & 7) * 8;
        short8 v = *(const short8*)&A2[(rowbase + j) * 256 + d0 + d8];
        #pragma unroll
        for (int t = 0; t < 8; t++) sB[j][d8 + t] = bs2f(v[t]);
    }
    for (int e = threadIdx.x; e < 1024; e += 256) {
        int j = e >> 4, d4 = (e & 15) * 4;
        *(float4*)&sX[j][d4] = *(const float4*)&X[(rowbase + j) * 256 + d0 + d4];
    }
    __syncthreads();
    float Av = bs2f(A1[(rowbase + i) * 256 + d0 + dl]);
    int js = fw ? (i + 1) : 0;
    int je = fw ? 64 : i;
    float den = 0.f, num = 0.f;
    for (int j = js; j < je; j++) {
        float z = (Av + sB[j][dl]) * 0.2f;
        float e2 = __expf(2.f * z);
        float t = 1.f - 2.f / (e2 + 1.f);
        float w = __expf(5.f * t);            // scores in [-5,5]
        den += w;
        num += w * sX[j][dl];
    }
    float out = (je > js) ? (num / den) : 0.f;
    H[(rowbase + i) * 256 + d0 + dl] = out;
}

// ---------- s2t pool: softmax over r of logits (bf16), weighted sum of H (f32) ----------
__global__ __launch_bounds__(256) void s2t_k(const short* __restrict__ L,
    const float* __restrict__ Hh, float* __restrict__ V)
{
    int bn = blockIdx.x, d = threadIdx.x;
    float m = -1e30f, den = 0.f, num = 0.f;
    for (int r = 0; r < 64; r++) {
        size_t idx = ((size_t)bn * 64 + r) * 256 + d;
        float l = bs2f(L[idx]), h = Hh[idx];
        if (l > m) {
            float sc = __expf(m - l);
            den *= sc; num *= sc; m = l;
        }
        float w = __expf(l - m);
        den += w; num += w * h;
    }
    V[(size_t)bn * 256 + d] = num / den;
}

// ---------- level-2 attention, row 0 only (idx == all zeros); bw row0 -> 0 ----------
__global__ __launch_bounds__(256) void attn2_k(const float* __restrict__ vW1,
    const float* __restrict__ vW2b, const float* __restrict__ V,
    float* __restrict__ O0, int fw)
{
    int b = blockIdx.x, d = threadIdx.x;
    float out = 0.f;
    if (fw) {
        float q = vW1[((size_t)b * 16) * 256 + d];
        float den = 0.f, num = 0.f;
        for (int j = 1; j < 16; j++) {
            float z = (q + vW2b[((size_t)b * 16 + j) * 256 + d]) * 0.2f;
            float e2 = __expf(2.f * z);
            float t = 1.f - 2.f / (e2 + 1.f);
            float w = __expf(5.f * t);
            den += w; num += w * V[((size_t)b * 16 + j) * 256 + d];
        }
        out = num / den;
    }
    O0[b * 256 + d] = out;
}

// ---------- gate, row 0 only: grid (4, 4), split-K x 64-col, f32 weights ----------
__global__ __launch_bounds__(256) void gate_k(const float* __restrict__ O0,
    const float* __restrict__ V, const float* __restrict__ gW1,
    const float* __restrict__ gW2, const float* __restrict__ gb,
    float* __restrict__ E0)
{
    __shared__ float so[256], sv[256];
    __shared__ float red[4][64];
    int b = blockIdx.x;
    int c = threadIdx.x & 63, ks = threadIdx.x >> 6;
    int gc = blockIdx.y * 64 + c;
    so[threadIdx.x] = O0[b * 256 + threadIdx.x];
    sv[threadIdx.x] = V[((size_t)b * 16) * 256 + threadIdx.x];
    __syncthreads();
    float acc = 0.f;
    int k0 = ks * 64;
    #pragma unroll 8
    for (int kk = 0; kk < 64; kk++) {
        int k = k0 + kk;
        acc += so[k] * gW1[(size_t)k * 256 + gc]
             + sv[k] * gW2[(size_t)k * 256 + gc];
    }
    red[ks][c] = acc;
    __syncthreads();
    if (ks == 0) {
        float a = red[0][c] + red[1][c] + red[2][c] + red[3][c] + gb[gc];
        float G = 1.f / (1.f + __expf(-a));
        E0[b * 256 + gc] = G * so[gc] + (1.f - G) * sv[gc];
    }
}

// ---------- fusion: grid (64, 4), split-K(4x192) x 64-col, f32 weights, f32 out ----------
__global__ __launch_bounds__(256) void fusion_k(const float* __restrict__ IN,
    const float* __restrict__ H, const float* __restrict__ E0,
    const float* __restrict__ fW1, const float* __restrict__ fb1,
    const float* __restrict__ fW2, const float* __restrict__ fb2,
    float* __restrict__ out, int p)
{
    __shared__ float cat[768];
    __shared__ float red1[4][64], red2[4][64];
    int bt = blockIdx.x, b = bt >> 4, t = bt & 15;
    int c = threadIdx.x & 63, ks = threadIdx.x >> 6;
    int gc = blockIdx.y * 64 + c;
    size_t xrow = ((size_t)b * 1024 + t) * 256;   // (b, n=0, r=t)
    cat[threadIdx.x]       = IN[xrow + threadIdx.x];
    cat[256 + threadIdx.x] = H[xrow + threadIdx.x];
    cat[512 + threadIdx.x] = E0[b * 256 + threadIdx.x];
    __syncthreads();
    float a1 = 0.f, a2 = 0.f;
    int k0 = ks * 192;
    #pragma unroll 8
    for (int kk = 0; kk < 192; kk++) {
        int k = k0 + kk;
        float cv = cat[k];
        a1 += cv * fW1[(size_t)k * 256 + gc];
        a2 += cv * fW2[(size_t)k * 256 + gc];
    }
    red1[ks][c] = a1; red2[ks][c] = a2;
    __syncthreads();
    if (ks == 0) {
        float s1 = red1[0][c] + red1[1][c] + red1[2][c] + red1[3][c] + fb1[gc];
        float s2 = red2[0][c] + red2[1][c] + red2[2][c] + red2[3][c] + fb2[gc];
        float fus = fmaxf(s1, 0.f);
        float Gf = 1.f / (1.f + __expf(-s2));
        float u = Gf * fus + (1.f - Gf) * cat[gc];
        out[((size_t)(b * 16 + t)) * 512 + (size_t)p * 256 + gc] = u;
    }
}

extern "C" void kernel_launch(void* const* d_in, const int* in_sizes, int n_in,
                              void* d_out, int out_size, void* d_ws, size_t ws_size,
                              hipStream_t stream)
{
    const float* x = (const float*)d_in[0];
    float* w = (float*)d_ws;
    float* buf_in  = w; w += 1048576;           // (B,N,R,D) post-fc, f32
    float* buf_h   = w; w += 1048576;           // h, f32
    short* A1bf    = (short*)w; w += 524288;    // xW1 / t1, bf16
    short* A2bf    = (short*)w; w += 524288;    // xW2+mb / logits, bf16
    float* buf_v   = w; w += 16384;             // (B*N, D)
    float* buf_vW1 = w; w += 16384;
    float* buf_vW2 = w; w += 16384;
    float* buf_o0  = w; w += 1024;              // (B, D)
    float* buf_e0  = w; w += 1024;
    short* wtH     = (short*)w; w += 327680;    // 10 x 65536 bf16 hi
    short* wtL     = (short*)w; w += 327680;    // 10 x 65536 bf16 lo
    // total 3,852,288 floats = 15.4 MB (< round-2-proven 17 MB)

    SrcPack sp;
    const int src_idx[5] = {0, 2, 3, 5, 7};  // fcW, mW1, mW2, s2tW1, s2tW
    for (int p = 0; p < 2; p++)
        for (int i = 0; i < 5; i++)
            sp.s[p * 5 + i] = (const float*)d_in[1 + p * 16 + src_idx[i]];
    transpose_k<<<dim3(16, 10), 256, 0, stream>>>(sp, wtH, wtL);

    for (int p = 0; p < 2; p++) {
        int base = 1 + p * 16;
        const float* fcb   = (const float*)d_in[base + 1];
        const float* mb    = (const float*)d_in[base + 4];
        const float* s2tb1 = (const float*)d_in[base + 6];
        const float* s2tb  = (const float*)d_in[base + 8];
        const float* gW1   = (const float*)d_in[base + 9];
        const float* gW2   = (const float*)d_in[base + 10];
        const float* gb    = (const float*)d_in[base + 11];
        const float* fW1   = (const float*)d_in[base + 12];
        const float* fb1   = (const float*)d_in[base + 13];
        const float* fW2   = (const float*)d_in[base + 14];
        const float* fb2   = (const float*)d_in[base + 15];
        int fw = (p == 0);

        const short* fcWh   = wtH + (size_t)(p * 5 + 0) * 65536;
        const short* fcWl   = wtL + (size_t)(p * 5 + 0) * 65536;
        const short* mW1h   = wtH + (size_t)(p * 5 + 1) * 65536;
        const short* mW1l   = wtL + (size_t)(p * 5 + 1) * 65536;
        const short* mW2h   = wtH + (size_t)(p * 5 + 2) * 65536;
        const short* mW2l   = wtL + (size_t)(p * 5 + 2) * 65536;
        const short* s2tW1h = wtH + (size_t)(p * 5 + 3) * 65536;
        const short* s2tW1l = wtL + (size_t)(p * 5 + 3) * 65536;
        const short* s2tWh  = wtH + (size_t)(p * 5 + 4) * 65536;
        const short* s2tWl  = wtL + (size_t)(p * 5 + 4) * 65536;

        gemm_k<1, 0, 1><<<dim3(64, 4), 256, 0, stream>>>(x, fcWh, fcWl, fcb, buf_in);
        gemm2_k<1><<<dim3(64, 8), 256, 0, stream>>>(buf_in, mW1h, mW1l, mW2h, mW2l, mb, A1bf, A2bf);
        attn1_k<<<dim3(16, 4, 64), 256, 0, stream>>>(A1bf, A2bf, buf_in, buf_h, fw);
        gemm_k<1, 1, 1><<<dim3(64, 4), 256, 0, stream>>>(buf_h, s2tW1h, s2tW1l, s2tb1, A1bf);
        gemm_k<0, 1, 0><<<dim3(64, 4), 256, 0, stream>>>(A1bf, s2tWh, s2tWl, s2tb, A2bf);
        s2t_k<<<64, 256, 0, stream>>>(A2bf, buf_h, buf_v);
        gemm2_k<0><<<dim3(1, 8), 256, 0, stream>>>(buf_v, mW1h, mW1l, mW2h, mW2l, mb, buf_vW1, buf_vW2);
        attn2_k<<<4, 256, 0, stream>>>(buf_vW1, buf_vW2, buf_v, buf_o0, fw);
        gate_k<<<dim3(4, 4), 256, 0, stream>>>(buf_o0, buf_v, gW1, gW2, gb, buf_e0);
        fusion_k<<<dim3(64, 4), 256, 0, stream>>>(buf_in, buf_h, buf_e0, fW1, fb1, fW2, fb2,
                                                  (float*)d_out, p);
    }
}

// Round 5
// 301.246 us; speedup vs baseline: 3.6740x; 1.2183x over previous
//
#include <hip/hip_runtime.h>
#include <hip/hip_bf16.h>

typedef __hip_bfloat16 BF16;
typedef __attribute__((ext_vector_type(8))) short short8;
typedef __attribute__((ext_vector_type(4))) short short4v;
typedef __attribute__((ext_vector_type(4))) float f32x4;

__device__ __forceinline__ short f2bs(float f){
    BF16 h = __float2bfloat16(f);
    return *(short*)&h;
}
__device__ __forceinline__ float bs2f(short s){
    BF16 h = *(BF16*)&s;
    return __bfloat162float(h);
}

// ---------- prep: transpose+split 10 f32 weight mats (256x256) to n-major bf16 hi/lo ----------
struct SrcPack { const float* s[10]; };

__global__ __launch_bounds__(256) void transpose_k(SrcPack p, short* __restrict__ Oh,
                                                   short* __restrict__ Ol)
{
    __shared__ float s[64][65];
    const float* W = p.s[blockIdx.y];
    short* oh = Oh + (size_t)blockIdx.y * 65536;
    short* ol = Ol + (size_t)blockIdx.y * 65536;
    int tr = (blockIdx.x >> 2) * 64, tc = (blockIdx.x & 3) * 64;
    #pragma unroll
    for (int i = 0; i < 16; i++) {
        int e = threadIdx.x + i * 256;
        int r = e >> 6, c = e & 63;
        s[c][r] = W[(size_t)(tr + r) * 256 + tc + c];
    }
    __syncthreads();
    #pragma unroll
    for (int i = 0; i < 16; i++) {
        int e = threadIdx.x + i * 256;
        int c2 = e >> 6, r2 = e & 63;
        float v = s[c2][r2];
        short hi = f2bs(v);
        short lo = f2bs(v - bs2f(hi));
        size_t oi = (size_t)(tc + c2) * 256 + tr + r2;
        oh[oi] = hi;
        ol[oi] = lo;
    }
}

// ---------- MFMA GEMM, split-bf16 precision ----------
// AM: 0 = A single bf16 plane (2 MFMA), 1 = A f32 split on the fly (3 MFMA),
//     2 = A dual bf16 planes (3 MFMA).
// OM: 0 = f32 out, 1 = bf16 out, 2 = dual bf16 plane out.
template<int AM, int OM, int RELU>
__device__ __forceinline__ void gemm_body(const void* __restrict__ A0,
    const void* __restrict__ Alo,
    const short* __restrict__ Wh, const short* __restrict__ Wl,
    const float* __restrict__ bias, void* __restrict__ O0, void* __restrict__ O1,
    int row0, int col0)
{
    constexpr int LDK = 72;
    __shared__ short sAh[64 * LDK];
    __shared__ short sAl[(AM == 0) ? 8 : 64 * LDK];
    __shared__ short sBh[64 * LDK];
    __shared__ short sBl[64 * LDK];
    int tid = threadIdx.x;
    int w = tid >> 6, l = tid & 63;
    int m = l & 15, q = l >> 4;
    int sr = w * 16 + m;

    f32x4 acc[4];
    #pragma unroll
    for (int cf = 0; cf < 4; cf++) acc[cf] = (f32x4)(0.f);

    for (int kh = 0; kh < 4; kh++) {
        int kbase = kh * 64;
        #pragma unroll
        for (int i = 0; i < 2; i++) {
            int kl = q * 8 + 32 * i;
            size_t gofs = (size_t)(row0 + sr) * 256 + kbase + kl;
            if (AM == 1) {
                const float* src = (const float*)A0 + gofs;
                float4 f0 = *(const float4*)src;
                float4 f1 = *(const float4*)(src + 4);
                short8 vh, vl;
                float tmp[8] = {f0.x, f0.y, f0.z, f0.w, f1.x, f1.y, f1.z, f1.w};
                #pragma unroll
                for (int j = 0; j < 8; j++) {
                    vh[j] = f2bs(tmp[j]);
                    vl[j] = f2bs(tmp[j] - bs2f(vh[j]));
                }
                *(short8*)&sAh[sr * LDK + kl] = vh;
                *(short8*)&sAl[sr * LDK + kl] = vl;
            } else if (AM == 2) {
                *(short8*)&sAh[sr * LDK + kl] = *(const short8*)((const short*)A0 + gofs);
                *(short8*)&sAl[sr * LDK + kl] = *(const short8*)((const short*)Alo + gofs);
            } else {
                *(short8*)&sAh[sr * LDK + kl] = *(const short8*)((const short*)A0 + gofs);
            }
            size_t gofsB = (size_t)(col0 + sr) * 256 + kbase + kl;
            *(short8*)&sBh[sr * LDK + kl] = *(const short8*)(Wh + gofsB);
            *(short8*)&sBl[sr * LDK + kl] = *(const short8*)(Wl + gofsB);
        }
        __syncthreads();
        #pragma unroll
        for (int ch = 0; ch < 2; ch++) {
            int k = ch * 32 + q * 8;
            short8 ah = *(const short8*)&sAh[(w * 16 + m) * LDK + k];
            short8 al = (AM != 0) ? *(const short8*)&sAl[(w * 16 + m) * LDK + k] : ah;
            #pragma unroll
            for (int cf = 0; cf < 4; cf++) {
                short8 bh = *(const short8*)&sBh[(cf * 16 + m) * LDK + k];
                short8 bl = *(const short8*)&sBl[(cf * 16 + m) * LDK + k];
                acc[cf] = __builtin_amdgcn_mfma_f32_16x16x32_bf16(ah, bh, acc[cf], 0, 0, 0);
                acc[cf] = __builtin_amdgcn_mfma_f32_16x16x32_bf16(ah, bl, acc[cf], 0, 0, 0);
                if (AM != 0)
                    acc[cf] = __builtin_amdgcn_mfma_f32_16x16x32_bf16(al, bh, acc[cf], 0, 0, 0);
            }
        }
        __syncthreads();
    }
    // C/D layout: col = lane&15, row = (lane>>4)*4 + reg (m89-verified)
    #pragma unroll
    for (int cf = 0; cf < 4; cf++) {
        int col = col0 + cf * 16 + m;
        float bv = bias ? bias[col] : 0.f;
        #pragma unroll
        for (int r = 0; r < 4; r++) {
            int row = row0 + w * 16 + q * 4 + r;
            float v = acc[cf][r] + bv;
            if (RELU) v = fmaxf(v, 0.f);
            size_t oi = (size_t)row * 256 + col;
            if (OM == 0) {
                ((float*)O0)[oi] = v;
            } else if (OM == 1) {
                ((short*)O0)[oi] = f2bs(v);
            } else {
                short hi = f2bs(v);
                ((short*)O0)[oi] = hi;
                ((short*)O1)[oi] = f2bs(v - bs2f(hi));
            }
        }
    }
}

template<int AM, int OM, int RELU>
__global__ __launch_bounds__(256) void gemm_k(const void* __restrict__ A0,
    const void* __restrict__ Alo, const short* __restrict__ Wh,
    const short* __restrict__ Wl, const float* __restrict__ bias,
    void* __restrict__ O0, void* __restrict__ O1)
{
    gemm_body<AM, OM, RELU>(A0, Alo, Wh, Wl, bias, O0, O1, blockIdx.x * 64, blockIdx.y * 64);
}

// fused dual GEMM (shared A): C1 = A@W1 ; C2 = A@W2 + b2 (grid.y 0..7)
template<int AM, int OM>
__global__ __launch_bounds__(256) void gemm2_k(const void* __restrict__ A0,
    const void* __restrict__ Alo,
    const short* __restrict__ W1h, const short* __restrict__ W1l,
    const short* __restrict__ W2h, const short* __restrict__ W2l,
    const float* __restrict__ bias2, void* __restrict__ C1, void* __restrict__ C2)
{
    int y = blockIdx.y;
    const short* Wh = (y < 4) ? W1h : W2h;
    const short* Wl = (y < 4) ? W1l : W2l;
    void* C = (y < 4) ? C1 : C2;
    const float* bias = (y < 4) ? nullptr : bias2;
    gemm_body<AM, OM, 0>(A0, Alo, Wh, Wl, bias, C, nullptr, blockIdx.x * 64, (y & 3) * 64);
}

// ---------- level-1 fused masked attention ----------
// grid (2 ihalf, 4 dchunk, 64 bn), 256 thr = 4 waves; wave handles 8 interleaved rows.
// A1,A2: bf16 logits; X = inH+inL planes; out: dual-plane H.
// w_ij = exp(5*tanh((A+B)/5)) = e^5 * exp(-10/(1+P_i*Q_j)), P=exp(0.4A), Q=exp(0.4B);
// e^5 cancels in softmax.
__global__ __launch_bounds__(256) void attn1_k(const short* __restrict__ A1,
    const short* __restrict__ A2, const short* __restrict__ Xh,
    const short* __restrict__ Xl, short* __restrict__ Hh, short* __restrict__ Hl, int fw)
{
    __shared__ float sQ[64][68];
    __shared__ float sX[64][68];
    int tid = threadIdx.x;
    int ih = blockIdx.x, d0 = blockIdx.y * 64, bn = blockIdx.z;
    size_t rowbase = (size_t)bn * 64;
    #pragma unroll
    for (int it = 0; it < 2; it++) {
        int e = tid + it * 256;
        int j = e >> 3, d8 = (e & 7) * 8;
        short8 qv = *(const short8*)&A2[(rowbase + j) * 256 + d0 + d8];
        short8 xh = *(const short8*)&Xh[(rowbase + j) * 256 + d0 + d8];
        short8 xl = *(const short8*)&Xl[(rowbase + j) * 256 + d0 + d8];
        #pragma unroll
        for (int t = 0; t < 8; t++) {
            sQ[j][d8 + t] = __expf(0.4f * bs2f(qv[t]));
            sX[j][d8 + t] = bs2f(xh[t]) + bs2f(xl[t]);
        }
    }
    __syncthreads();
    int wv = tid >> 6, dl = tid & 63;
    int sub = ih * 4 + wv;
    #pragma unroll
    for (int t = 0; t < 8; t++) {
        int i = sub + 8 * t;
        float P = __expf(0.4f * bs2f(A1[(rowbase + i) * 256 + d0 + dl]));
        int js = fw ? (i + 1) : 0;
        int je = fw ? 64 : i;
        float den = 0.f, num = 0.f;
        for (int j = js; j < je; j++) {
            float u = P * sQ[j][dl];
            float r = __builtin_amdgcn_rcpf(1.f + u);
            float w = __expf(-10.f * r);
            den += w;
            num += w * sX[j][dl];
        }
        float out = (je > js) ? (num * __builtin_amdgcn_rcpf(den)) : 0.f;
        short hi = f2bs(out);
        size_t oi = (rowbase + i) * 256 + d0 + dl;
        Hh[oi] = hi;
        Hl[oi] = f2bs(out - bs2f(hi));
    }
}

// ---------- s2t pool: grid (4 dchunk, 64 bn); 4-way r-split + LDS merge ----------
__global__ __launch_bounds__(256) void s2t_k(const short* __restrict__ L,
    const short* __restrict__ Hh, const short* __restrict__ Hl, float* __restrict__ V)
{
    __shared__ float sm[4][64], sd[4][64], sn[4][64];
    int dl = threadIdx.x & 63, rq = threadIdx.x >> 6;
    int d = blockIdx.x * 64 + dl;
    int bn = blockIdx.y;
    float m = -1e30f, den = 0.f, num = 0.f;
    #pragma unroll
    for (int rr = 0; rr < 16; rr++) {
        int r = rq * 16 + rr;
        size_t idx = ((size_t)bn * 64 + r) * 256 + d;
        float l = bs2f(L[idx]);
        float h = bs2f(Hh[idx]) + bs2f(Hl[idx]);
        if (l > m) {
            float sc = __expf(m - l);
            den *= sc; num *= sc; m = l;
        }
        float w = __expf(l - m);
        den += w; num += w * h;
    }
    sm[rq][dl] = m; sd[rq][dl] = den; sn[rq][dl] = num;
    __syncthreads();
    if (rq == 0) {
        float M = fmaxf(fmaxf(sm[0][dl], sm[1][dl]), fmaxf(sm[2][dl], sm[3][dl]));
        float D = 0.f, Nn = 0.f;
        #pragma unroll
        for (int k = 0; k < 4; k++) {
            float sc = __expf(sm[k][dl] - M);
            D += sd[k][dl] * sc;
            Nn += sn[k][dl] * sc;
        }
        V[(size_t)bn * 256 + d] = Nn / D;
    }
}

// ---------- level-2 attention, row 0 only (idx == all zeros); bw row0 -> 0 ----------
__global__ __launch_bounds__(256) void attn2_k(const float* __restrict__ vW1,
    const float* __restrict__ vW2b, const float* __restrict__ V,
    float* __restrict__ O0, int fw)
{
    int b = blockIdx.x, d = threadIdx.x;
    float out = 0.f;
    if (fw) {
        float q = vW1[((size_t)b * 16) * 256 + d];
        float den = 0.f, num = 0.f;
        for (int j = 1; j < 16; j++) {
            float z = (q + vW2b[((size_t)b * 16 + j) * 256 + d]) * 0.2f;
            float e2 = __expf(2.f * z);
            float t = 1.f - 2.f / (e2 + 1.f);
            float w = __expf(5.f * t);
            den += w; num += w * V[((size_t)b * 16 + j) * 256 + d];
        }
        out = num / den;
    }
    O0[b * 256 + d] = out;
}

// ---------- gate, row 0 only: grid (4, 4), split-K x 64-col, f32 weights ----------
__global__ __launch_bounds__(256) void gate_k(const float* __restrict__ O0,
    const float* __restrict__ V, const float* __restrict__ gW1,
    const float* __restrict__ gW2, const float* __restrict__ gb,
    float* __restrict__ E0)
{
    __shared__ float so[256], sv[256];
    __shared__ float red[4][64];
    int b = blockIdx.x;
    int c = threadIdx.x & 63, ks = threadIdx.x >> 6;
    int gc = blockIdx.y * 64 + c;
    so[threadIdx.x] = O0[b * 256 + threadIdx.x];
    sv[threadIdx.x] = V[((size_t)b * 16) * 256 + threadIdx.x];
    __syncthreads();
    float acc = 0.f;
    int k0 = ks * 64;
    #pragma unroll 8
    for (int kk = 0; kk < 64; kk++) {
        int k = k0 + kk;
        acc += so[k] * gW1[(size_t)k * 256 + gc]
             + sv[k] * gW2[(size_t)k * 256 + gc];
    }
    red[ks][c] = acc;
    __syncthreads();
    if (ks == 0) {
        float a = red[0][c] + red[1][c] + red[2][c] + red[3][c] + gb[gc];
        float G = 1.f / (1.f + __expf(-a));
        E0[b * 256 + gc] = G * so[gc] + (1.f - G) * sv[gc];
    }
}

// ---------- fusion: grid (64, 4), split-K(4x192) x 64-col, f32 weights, f32 out ----------
__global__ __launch_bounds__(256) void fusion_k(const short* __restrict__ INh,
    const short* __restrict__ INl, const short* __restrict__ Hh,
    const short* __restrict__ Hl, const float* __restrict__ E0,
    const float* __restrict__ fW1, const float* __restrict__ fb1,
    const float* __restrict__ fW2, const float* __restrict__ fb2,
    float* __restrict__ out, int p)
{
    __shared__ float cat[768];
    __shared__ float red1[4][64], red2[4][64];
    int bt = blockIdx.x, b = bt >> 4, t = bt & 15;
    int c = threadIdx.x & 63, ks = threadIdx.x >> 6;
    int gc = blockIdx.y * 64 + c;
    size_t xrow = ((size_t)b * 1024 + t) * 256;   // (b, n=0, r=t)
    cat[threadIdx.x]       = bs2f(INh[xrow + threadIdx.x]) + bs2f(INl[xrow + threadIdx.x]);
    cat[256 + threadIdx.x] = bs2f(Hh[xrow + threadIdx.x]) + bs2f(Hl[xrow + threadIdx.x]);
    cat[512 + threadIdx.x] = E0[b * 256 + threadIdx.x];
    __syncthreads();
    float a1 = 0.f, a2 = 0.f;
    int k0 = ks * 192;
    #pragma unroll 8
    for (int kk = 0; kk < 192; kk++) {
        int k = k0 + kk;
        float cv = cat[k];
        a1 += cv * fW1[(size_t)k * 256 + gc];
        a2 += cv * fW2[(size_t)k * 256 + gc];
    }
    red1[ks][c] = a1; red2[ks][c] = a2;
    __syncthreads();
    if (ks == 0) {
        float s1 = red1[0][c] + red1[1][c] + red1[2][c] + red1[3][c] + fb1[gc];
        float s2 = red2[0][c] + red2[1][c] + red2[2][c] + red2[3][c] + fb2[gc];
        float fus = fmaxf(s1, 0.f);
        float Gf = 1.f / (1.f + __expf(-s2));
        float u = Gf * fus + (1.f - Gf) * cat[gc];
        out[((size_t)(b * 16 + t)) * 512 + (size_t)p * 256 + gc] = u;
    }
}

extern "C" void kernel_launch(void* const* d_in, const int* in_sizes, int n_in,
                              void* d_out, int out_size, void* d_ws, size_t ws_size,
                              hipStream_t stream)
{
    const float* x = (const float*)d_in[0];
    char* base = (char*)d_ws;
    short* inH  = (short*)base; base += 2097152;
    short* inL  = (short*)base; base += 2097152;
    short* hH   = (short*)base; base += 2097152;
    short* hL   = (short*)base; base += 2097152;
    short* A1bf = (short*)base; base += 2097152;   // xW1 logits -> reused as t1
    short* A2bf = (short*)base; base += 2097152;   // xW2+mb logits -> reused as s2t logits
    short* wtH  = (short*)base; base += 1310720;   // 10 x 65536 bf16 hi
    short* wtL  = (short*)base; base += 1310720;   // 10 x 65536 bf16 lo
    float* buf_v   = (float*)base; base += 65536;  // (B*N, D)
    float* buf_vW1 = (float*)base; base += 65536;
    float* buf_vW2 = (float*)base; base += 65536;
    float* buf_o0  = (float*)base; base += 4096;   // (B, D)
    float* buf_e0  = (float*)base; base += 4096;
    // total ~15.4 MB (round-4 proven)

    SrcPack sp;
    const int src_idx[5] = {0, 2, 3, 5, 7};  // fcW, mW1, mW2, s2tW1, s2tW
    for (int p = 0; p < 2; p++)
        for (int i = 0; i < 5; i++)
            sp.s[p * 5 + i] = (const float*)d_in[1 + p * 16 + src_idx[i]];
    transpose_k<<<dim3(16, 10), 256, 0, stream>>>(sp, wtH, wtL);

    for (int p = 0; p < 2; p++) {
        int baseI = 1 + p * 16;
        const float* fcb   = (const float*)d_in[baseI + 1];
        const float* mb    = (const float*)d_in[baseI + 4];
        const float* s2tb1 = (const float*)d_in[baseI + 6];
        const float* s2tb  = (const float*)d_in[baseI + 8];
        const float* gW1   = (const float*)d_in[baseI + 9];
        const float* gW2   = (const float*)d_in[baseI + 10];
        const float* gb    = (const float*)d_in[baseI + 11];
        const float* fW1   = (const float*)d_in[baseI + 12];
        const float* fb1   = (const float*)d_in[baseI + 13];
        const float* fW2   = (const float*)d_in[baseI + 14];
        const float* fb2   = (const float*)d_in[baseI + 15];
        int fw = (p == 0);

        const short* fcWh   = wtH + (size_t)(p * 5 + 0) * 65536;
        const short* fcWl   = wtL + (size_t)(p * 5 + 0) * 65536;
        const short* mW1h   = wtH + (size_t)(p * 5 + 1) * 65536;
        const short* mW1l   = wtL + (size_t)(p * 5 + 1) * 65536;
        const short* mW2h   = wtH + (size_t)(p * 5 + 2) * 65536;
        const short* mW2l   = wtL + (size_t)(p * 5 + 2) * 65536;
        const short* s2tW1h = wtH + (size_t)(p * 5 + 3) * 65536;
        const short* s2tW1l = wtL + (size_t)(p * 5 + 3) * 65536;
        const short* s2tWh  = wtH + (size_t)(p * 5 + 4) * 65536;
        const short* s2tWl  = wtL + (size_t)(p * 5 + 4) * 65536;

        gemm_k<1, 2, 1><<<dim3(64, 4), 256, 0, stream>>>(x, nullptr, fcWh, fcWl, fcb, inH, inL);
        gemm2_k<2, 1><<<dim3(64, 8), 256, 0, stream>>>(inH, inL, mW1h, mW1l, mW2h, mW2l, mb,
                                                       A1bf, A2bf);
        attn1_k<<<dim3(2, 4, 64), 256, 0, stream>>>(A1bf, A2bf, inH, inL, hH, hL, fw);
        gemm_k<2, 1, 1><<<dim3(64, 4), 256, 0, stream>>>(hH, hL, s2tW1h, s2tW1l, s2tb1,
                                                         A1bf, nullptr);
        gemm_k<0, 1, 0><<<dim3(64, 4), 256, 0, stream>>>(A1bf, nullptr, s2tWh, s2tWl, s2tb,
                                                         A2bf, nullptr);
        s2t_k<<<dim3(4, 64), 256, 0, stream>>>(A2bf, hH, hL, buf_v);
        gemm2_k<1, 0><<<dim3(1, 8), 256, 0, stream>>>(buf_v, nullptr, mW1h, mW1l, mW2h, mW2l,
                                                      mb, buf_vW1, buf_vW2);
        attn2_k<<<4, 256, 0, stream>>>(buf_vW1, buf_vW2, buf_v, buf_o0, fw);
        gate_k<<<dim3(4, 4), 256, 0, stream>>>(buf_o0, buf_v, gW1, gW2, gb, buf_e0);
        fusion_k<<<dim3(64, 4), 256, 0, stream>>>(inH, inL, hH, hL, buf_e0,
                                                  fW1, fb1, fW2, fb2, (float*)d_out, p);
    }
}

// Round 6
// 225.765 us; speedup vs baseline: 4.9023x; 1.3343x over previous
//
#include <hip/hip_runtime.h>
#include <hip/hip_bf16.h>

typedef __hip_bfloat16 BF16;
typedef __attribute__((ext_vector_type(8))) short short8;
typedef __attribute__((ext_vector_type(4))) float f32x4;

#define MFMA_B16(a,b,c) __builtin_amdgcn_mfma_f32_16x16x32_bf16((a),(b),(c),0,0,0)

__device__ __forceinline__ short f2bs(float f){ BF16 h = __float2bfloat16(f); return *(short*)&h; }
__device__ __forceinline__ float bs2f(short s){ BF16 h = *(BF16*)&s; return __bfloat162float(h); }

// ---------- prep: transpose+split 10 f32 weight mats (256x256) to n-major bf16 hi/lo ----------
struct SrcPack { const float* s[10]; };

__global__ __launch_bounds__(256) void transpose_k(SrcPack p, short* __restrict__ Oh,
                                                   short* __restrict__ Ol)
{
    __shared__ float s[64][65];
    const float* W = p.s[blockIdx.y];
    short* oh = Oh + (size_t)blockIdx.y * 65536;
    short* ol = Ol + (size_t)blockIdx.y * 65536;
    int tr = (blockIdx.x >> 2) * 64, tc = (blockIdx.x & 3) * 64;
    #pragma unroll
    for (int i = 0; i < 16; i++) {
        int e = threadIdx.x + i * 256;
        int r = e >> 6, c = e & 63;
        s[c][r] = W[(size_t)(tr + r) * 256 + tc + c];
    }
    __syncthreads();
    #pragma unroll
    for (int i = 0; i < 16; i++) {
        int e = threadIdx.x + i * 256;
        int c2 = e >> 6, r2 = e & 63;
        float v = s[c2][r2];
        short hi = f2bs(v);
        short lo = f2bs(v - bs2f(hi));
        size_t oi = (size_t)(tc + c2) * 256 + tr + r2;
        oh[oi] = hi;
        ol[oi] = lo;
    }
}

// ---------- generic MFMA GEMM body, split-bf16 precision ----------
// AM: 0 = A single bf16 plane (2 MFMA), 1 = A f32 split on the fly (3 MFMA),
//     2 = A dual bf16 planes (3 MFMA).  OM: 0 = f32, 1 = bf16, 2 = dual planes.
template<int AM, int OM, int RELU>
__device__ __forceinline__ void gemm_body(const void* __restrict__ A0,
    const void* __restrict__ Alo,
    const short* __restrict__ Wh, const short* __restrict__ Wl,
    const float* __restrict__ bias, void* __restrict__ O0, void* __restrict__ O1,
    int row0, int col0)
{
    constexpr int LDK = 72;
    __shared__ short sAh[64 * LDK];
    __shared__ short sAl[(AM == 0) ? 8 : 64 * LDK];
    __shared__ short sBh[64 * LDK];
    __shared__ short sBl[64 * LDK];
    int tid = threadIdx.x;
    int w = tid >> 6, l = tid & 63;
    int m = l & 15, q = l >> 4;
    int sr = w * 16 + m;

    f32x4 acc[4];
    #pragma unroll
    for (int cf = 0; cf < 4; cf++) acc[cf] = (f32x4)(0.f);

    for (int kh = 0; kh < 4; kh++) {
        int kbase = kh * 64;
        #pragma unroll
        for (int i = 0; i < 2; i++) {
            int kl = q * 8 + 32 * i;
            size_t gofs = (size_t)(row0 + sr) * 256 + kbase + kl;
            if (AM == 1) {
                const float* src = (const float*)A0 + gofs;
                float4 f0 = *(const float4*)src;
                float4 f1 = *(const float4*)(src + 4);
                short8 vh, vl;
                float tmp[8] = {f0.x, f0.y, f0.z, f0.w, f1.x, f1.y, f1.z, f1.w};
                #pragma unroll
                for (int j = 0; j < 8; j++) {
                    vh[j] = f2bs(tmp[j]);
                    vl[j] = f2bs(tmp[j] - bs2f(vh[j]));
                }
                *(short8*)&sAh[sr * LDK + kl] = vh;
                *(short8*)&sAl[sr * LDK + kl] = vl;
            } else if (AM == 2) {
                *(short8*)&sAh[sr * LDK + kl] = *(const short8*)((const short*)A0 + gofs);
                *(short8*)&sAl[sr * LDK + kl] = *(const short8*)((const short*)Alo + gofs);
            } else {
                *(short8*)&sAh[sr * LDK + kl] = *(const short8*)((const short*)A0 + gofs);
            }
            size_t gofsB = (size_t)(col0 + sr) * 256 + kbase + kl;
            *(short8*)&sBh[sr * LDK + kl] = *(const short8*)(Wh + gofsB);
            *(short8*)&sBl[sr * LDK + kl] = *(const short8*)(Wl + gofsB);
        }
        __syncthreads();
        #pragma unroll
        for (int ch = 0; ch < 2; ch++) {
            int k = ch * 32 + q * 8;
            short8 ah = *(const short8*)&sAh[(w * 16 + m) * LDK + k];
            short8 al = (AM != 0) ? *(const short8*)&sAl[(w * 16 + m) * LDK + k] : ah;
            #pragma unroll
            for (int cf = 0; cf < 4; cf++) {
                short8 bh = *(const short8*)&sBh[(cf * 16 + m) * LDK + k];
                short8 bl = *(const short8*)&sBl[(cf * 16 + m) * LDK + k];
                acc[cf] = MFMA_B16(ah, bh, acc[cf]);
                acc[cf] = MFMA_B16(ah, bl, acc[cf]);
                if (AM != 0)
                    acc[cf] = MFMA_B16(al, bh, acc[cf]);
            }
        }
        __syncthreads();
    }
    // C/D layout: col = lane&15, row = (lane>>4)*4 + reg (m89-verified)
    #pragma unroll
    for (int cf = 0; cf < 4; cf++) {
        int col = col0 + cf * 16 + m;
        float bv = bias ? bias[col] : 0.f;
        #pragma unroll
        for (int r = 0; r < 4; r++) {
            int row = row0 + w * 16 + q * 4 + r;
            float v = acc[cf][r] + bv;
            if (RELU) v = fmaxf(v, 0.f);
            size_t oi = (size_t)row * 256 + col;
            if (OM == 0) {
                ((float*)O0)[oi] = v;
            } else if (OM == 1) {
                ((short*)O0)[oi] = f2bs(v);
            } else {
                short hi = f2bs(v);
                ((short*)O0)[oi] = hi;
                ((short*)O1)[oi] = f2bs(v - bs2f(hi));
            }
        }
    }
}

// batched-direction generic GEMM
struct GDir { const void* A0; const void* Al; const short* Wh; const short* Wl;
              const float* bias; void* O0; void* O1; };

template<int AM, int OM, int RELU>
__global__ __launch_bounds__(256) void gemm_k(GDir p0, GDir p1)
{
    GDir p = blockIdx.z ? p1 : p0;
    gemm_body<AM, OM, RELU>(p.A0, p.Al, p.Wh, p.Wl, p.bias, p.O0, p.O1,
                            blockIdx.x * 64, blockIdx.y * 64);
}

// small dual GEMM (M=64): vW1 = v@mW1, vW2 = v@mW2+mb; grid (1, 8, 2)
struct G2Dir { const float* A; const short* W1h; const short* W1l;
               const short* W2h; const short* W2l; const float* b2;
               float* C1; float* C2; };

__global__ __launch_bounds__(256) void gemm2s_k(G2Dir p0, G2Dir p1)
{
    G2Dir p = blockIdx.z ? p1 : p0;
    int y = blockIdx.y;
    const short* Wh = (y < 4) ? p.W1h : p.W2h;
    const short* Wl = (y < 4) ? p.W1l : p.W2l;
    void* C = (y < 4) ? (void*)p.C1 : (void*)p.C2;
    const float* bias = (y < 4) ? nullptr : p.b2;
    gemm_body<1, 0, 0>(p.A, nullptr, Wh, Wl, bias, C, nullptr, 0, (y & 3) * 64);
}

// ---------- fused dual mSA-GEMM + level-1 masked attention ----------
// Block (bn, dchunk, dir): computes A1 = in@mW1 and A2 = in@mW2 + mb for its
// 64x64 tile, transforms to P = exp(0.4*A1), Q = exp(0.4*A2) in LDS (overlaid
// on GEMM staging), loads X tile, runs masked online softmax, writes dual-plane h.
// w_ij = exp(5*tanh(s/5)) = e^5 * exp(-10/(1+P_i*Q_j)); e^5 cancels in softmax.
struct MbloDir { const short* Ah; const short* Al;
                 const short* W1h; const short* W1l;
                 const short* W2h; const short* W2l;
                 const float* mb; short* Hh; short* Hl; int fw; };

__global__ __launch_bounds__(256) void mblo_k(MbloDir p0, MbloDir p1)
{
    __shared__ char smraw[55296] __attribute__((aligned(16)));
    short* gAh  = (short*)smraw;            // 64*72
    short* gAl  = gAh + 4608;
    short* gB1h = gAh + 9216;
    short* gB1l = gAh + 13824;
    short* gB2h = gAh + 18432;
    short* gB2l = gAh + 23040;
    float* aP = (float*)smraw;              // 64*68
    float* aQ = aP + 4352;
    float* aX = aP + 8704;

    MbloDir p = blockIdx.z ? p1 : p0;
    int tid = threadIdx.x;
    int w = tid >> 6, l = tid & 63;
    int m = l & 15, q = l >> 4;
    int sr = w * 16 + m;
    int row0 = blockIdx.x * 64, d0 = blockIdx.y * 64;

    f32x4 acc1[4], acc2[4];
    #pragma unroll
    for (int cf = 0; cf < 4; cf++) { acc1[cf] = (f32x4)(0.f); acc2[cf] = (f32x4)(0.f); }

    for (int kh = 0; kh < 4; kh++) {
        int kbase = kh * 64;
        #pragma unroll
        for (int i = 0; i < 2; i++) {
            int kl = q * 8 + 32 * i;
            size_t ga = (size_t)(row0 + sr) * 256 + kbase + kl;
            *(short8*)&gAh[sr * 72 + kl] = *(const short8*)(p.Ah + ga);
            *(short8*)&gAl[sr * 72 + kl] = *(const short8*)(p.Al + ga);
            size_t gb = (size_t)(d0 + sr) * 256 + kbase + kl;
            *(short8*)&gB1h[sr * 72 + kl] = *(const short8*)(p.W1h + gb);
            *(short8*)&gB1l[sr * 72 + kl] = *(const short8*)(p.W1l + gb);
            *(short8*)&gB2h[sr * 72 + kl] = *(const short8*)(p.W2h + gb);
            *(short8*)&gB2l[sr * 72 + kl] = *(const short8*)(p.W2l + gb);
        }
        __syncthreads();
        #pragma unroll
        for (int ch = 0; ch < 2; ch++) {
            int k = ch * 32 + q * 8;
            short8 ah = *(const short8*)&gAh[(w * 16 + m) * 72 + k];
            short8 al = *(const short8*)&gAl[(w * 16 + m) * 72 + k];
            #pragma unroll
            for (int cf = 0; cf < 4; cf++) {
                int bofs = (cf * 16 + m) * 72 + k;
                short8 b1h = *(const short8*)&gB1h[bofs];
                short8 b1l = *(const short8*)&gB1l[bofs];
                acc1[cf] = MFMA_B16(ah, b1h, acc1[cf]);
                acc1[cf] = MFMA_B16(ah, b1l, acc1[cf]);
                acc1[cf] = MFMA_B16(al, b1h, acc1[cf]);
                short8 b2h = *(const short8*)&gB2h[bofs];
                short8 b2l = *(const short8*)&gB2l[bofs];
                acc2[cf] = MFMA_B16(ah, b2h, acc2[cf]);
                acc2[cf] = MFMA_B16(ah, b2l, acc2[cf]);
                acc2[cf] = MFMA_B16(al, b2h, acc2[cf]);
            }
        }
        __syncthreads();   // also guards the union overwrite below
    }
    // epilogue: P/Q into LDS (overlays GEMM staging; all LDS reads drained by barrier)
    #pragma unroll
    for (int cf = 0; cf < 4; cf++) {
        int col = cf * 16 + m;
        float mbv = p.mb[d0 + col];
        #pragma unroll
        for (int r = 0; r < 4; r++) {
            int row = w * 16 + q * 4 + r;
            aP[row * 68 + col] = __expf(0.4f * acc1[cf][r]);
            aQ[row * 68 + col] = __expf(0.4f * (acc2[cf][r] + mbv));
        }
    }
    #pragma unroll
    for (int it = 0; it < 2; it++) {
        int e = tid + it * 256;
        int j = e >> 3, d8 = (e & 7) * 8;
        short8 xh = *(const short8*)(p.Ah + (size_t)(row0 + j) * 256 + d0 + d8);
        short8 xl = *(const short8*)(p.Al + (size_t)(row0 + j) * 256 + d0 + d8);
        #pragma unroll
        for (int t = 0; t < 8; t++)
            aX[j * 68 + d8 + t] = bs2f(xh[t]) + bs2f(xl[t]);
    }
    __syncthreads();
    // masked attention: wave w handles rows {w, w+4, ..., w+60}
    for (int t = 0; t < 16; t++) {
        int i = w + 4 * t;
        float P = aP[i * 68 + l];
        int js = p.fw ? (i + 1) : 0;
        int je = p.fw ? 64 : i;
        float den = 0.f, num = 0.f;
        for (int j = js; j < je; j++) {
            float u = P * aQ[j * 68 + l];
            float r = __builtin_amdgcn_rcpf(1.f + u);
            float wgt = __expf(-10.f * r);
            den += wgt;
            num += wgt * aX[j * 68 + l];
        }
        float out = (je > js) ? (num * __builtin_amdgcn_rcpf(den)) : 0.f;
        short hi = f2bs(out);
        size_t oi = (size_t)(row0 + i) * 256 + d0 + l;
        p.Hh[oi] = hi;
        p.Hl[oi] = f2bs(out - bs2f(hi));
    }
}

// ---------- fused s2t logits GEMM + softmax pool ----------
// Block (bn, dchunk, dir): logits tile = t1@s2tW + s2tb for rows bn*64..+63,
// then softmax over r (entire domain is in-block) weighted by h -> v chunk.
struct PoolDir { const short* T1; const short* Wh; const short* Wl; const float* bias;
                 const short* Hh; const short* Hl; float* V; };

__global__ __launch_bounds__(256) void s2t_pool_k(PoolDir p0, PoolDir p1)
{
    __shared__ char smraw[37888] __attribute__((aligned(16)));
    short* gAh = (short*)smraw;             // 64*72
    short* gBh = gAh + 4608;
    short* gBl = gAh + 9216;
    float* aL = (float*)smraw;              // 64*68
    float* aH = aL + 4352;
    float* rm = aL + 8704;                  // 4*64
    float* rd = aL + 8960;
    float* rn = aL + 9216;

    PoolDir p = blockIdx.z ? p1 : p0;
    int tid = threadIdx.x;
    int w = tid >> 6, l = tid & 63;
    int m = l & 15, q = l >> 4;
    int sr = w * 16 + m;
    int row0 = blockIdx.x * 64, d0 = blockIdx.y * 64;

    f32x4 acc[4];
    #pragma unroll
    for (int cf = 0; cf < 4; cf++) acc[cf] = (f32x4)(0.f);

    for (int kh = 0; kh < 4; kh++) {
        int kbase = kh * 64;
        #pragma unroll
        for (int i = 0; i < 2; i++) {
            int kl = q * 8 + 32 * i;
            *(short8*)&gAh[sr * 72 + kl] =
                *(const short8*)(p.T1 + (size_t)(row0 + sr) * 256 + kbase + kl);
            size_t gb = (size_t)(d0 + sr) * 256 + kbase + kl;
            *(short8*)&gBh[sr * 72 + kl] = *(const short8*)(p.Wh + gb);
            *(short8*)&gBl[sr * 72 + kl] = *(const short8*)(p.Wl + gb);
        }
        __syncthreads();
        #pragma unroll
        for (int ch = 0; ch < 2; ch++) {
            int k = ch * 32 + q * 8;
            short8 ah = *(const short8*)&gAh[(w * 16 + m) * 72 + k];
            #pragma unroll
            for (int cf = 0; cf < 4; cf++) {
                int bofs = (cf * 16 + m) * 72 + k;
                short8 bh = *(const short8*)&gBh[bofs];
                short8 bl = *(const short8*)&gBl[bofs];
                acc[cf] = MFMA_B16(ah, bh, acc[cf]);
                acc[cf] = MFMA_B16(ah, bl, acc[cf]);
            }
        }
        __syncthreads();
    }
    // logits -> LDS (overlay safe past barrier)
    #pragma unroll
    for (int cf = 0; cf < 4; cf++) {
        int col = cf * 16 + m;
        float bv = p.bias[d0 + col];
        #pragma unroll
        for (int r = 0; r < 4; r++) {
            int row = w * 16 + q * 4 + r;
            aL[row * 68 + col] = acc[cf][r] + bv;
        }
    }
    #pragma unroll
    for (int it = 0; it < 2; it++) {
        int e = tid + it * 256;
        int j = e >> 3, d8 = (e & 7) * 8;
        short8 xh = *(const short8*)(p.Hh + (size_t)(row0 + j) * 256 + d0 + d8);
        short8 xl = *(const short8*)(p.Hl + (size_t)(row0 + j) * 256 + d0 + d8);
        #pragma unroll
        for (int t = 0; t < 8; t++)
            aH[j * 68 + d8 + t] = bs2f(xh[t]) + bs2f(xl[t]);
    }
    __syncthreads();
    // online softmax over r, 4-way split + merge
    int dl = tid & 63, rq = tid >> 6;
    float mx = -1e30f, den = 0.f, num = 0.f;
    #pragma unroll
    for (int rr = 0; rr < 16; rr++) {
        int r = rq * 16 + rr;
        float lv = aL[r * 68 + dl];
        float hv = aH[r * 68 + dl];
        if (lv > mx) {
            float sc = __expf(mx - lv);
            den *= sc; num *= sc; mx = lv;
        }
        float wgt = __expf(lv - mx);
        den += wgt; num += wgt * hv;
    }
    rm[rq * 64 + dl] = mx; rd[rq * 64 + dl] = den; rn[rq * 64 + dl] = num;
    __syncthreads();
    if (rq == 0) {
        float M = fmaxf(fmaxf(rm[dl], rm[64 + dl]), fmaxf(rm[128 + dl], rm[192 + dl]));
        float D = 0.f, Nn = 0.f;
        #pragma unroll
        for (int k = 0; k < 4; k++) {
            float sc = __expf(rm[k * 64 + dl] - M);
            D += rd[k * 64 + dl] * sc;
            Nn += rn[k * 64 + dl] * sc;
        }
        p.V[(size_t)blockIdx.x * 256 + d0 + dl] = Nn / D;
    }
}

// ---------- fused level-2 attention (row 0) + gate ----------
// grid (b=4, dchunk=4, dir=2); phase1: all threads compute o0[k]; phase2: split-K gate.
struct GateDir { const float* vW1; const float* vW2; const float* V;
                 const float* gW1; const float* gW2; const float* gb;
                 float* E0; int fw; };

__global__ __launch_bounds__(256) void attn2gate_k(GateDir p0, GateDir p1)
{
    GateDir p = blockIdx.z ? p1 : p0;
    __shared__ float so[256], sv[256], red[4][64];
    int b = blockIdx.x, k = threadIdx.x;
    float o = 0.f;
    if (p.fw) {
        float qv = p.vW1[(size_t)(b * 16) * 256 + k];
        float den = 0.f, num = 0.f;
        for (int j = 1; j < 16; j++) {
            float z = (qv + p.vW2[(size_t)(b * 16 + j) * 256 + k]) * 0.2f;
            float e2 = __expf(2.f * z);
            float t = 1.f - 2.f / (e2 + 1.f);
            float wgt = __expf(5.f * t);
            den += wgt; num += wgt * p.V[(size_t)(b * 16 + j) * 256 + k];
        }
        o = num / den;
    }
    so[k] = o;
    sv[k] = p.V[(size_t)(b * 16) * 256 + k];
    __syncthreads();
    int c = k & 63, ks = k >> 6;
    int gc = blockIdx.y * 64 + c;
    float acc = 0.f;
    int k0 = ks * 64;
    #pragma unroll 8
    for (int kk = 0; kk < 64; kk++) {
        int kx = k0 + kk;
        acc += so[kx] * p.gW1[(size_t)kx * 256 + gc] + sv[kx] * p.gW2[(size_t)kx * 256 + gc];
    }
    red[ks][c] = acc;
    __syncthreads();
    if (ks == 0) {
        float a = red[0][c] + red[1][c] + red[2][c] + red[3][c] + p.gb[gc];
        float G = 1.f / (1.f + __expf(-a));
        p.E0[b * 256 + gc] = G * so[gc] + (1.f - G) * sv[gc];
    }
}

// ---------- fusion: grid (64 bt, 4 dchunk, 2 dir), split-K(4x192) x 64-col ----------
struct FuseDir { const short* INh; const short* INl; const short* Hh; const short* Hl;
                 const float* E0; const float* fW1; const float* fb1;
                 const float* fW2; const float* fb2; };

__global__ __launch_bounds__(256) void fusion_k(FuseDir p0, FuseDir p1, float* __restrict__ out)
{
    FuseDir p = blockIdx.z ? p1 : p0;
    __shared__ float cat[768];
    __shared__ float red1[4][64], red2[4][64];
    int bt = blockIdx.x, b = bt >> 4, t = bt & 15;
    int c = threadIdx.x & 63, ks = threadIdx.x >> 6;
    int gc = blockIdx.y * 64 + c;
    size_t xrow = ((size_t)b * 1024 + t) * 256;   // (b, n=0, r=t)
    cat[threadIdx.x]       = bs2f(p.INh[xrow + threadIdx.x]) + bs2f(p.INl[xrow + threadIdx.x]);
    cat[256 + threadIdx.x] = bs2f(p.Hh[xrow + threadIdx.x]) + bs2f(p.Hl[xrow + threadIdx.x]);
    cat[512 + threadIdx.x] = p.E0[b * 256 + threadIdx.x];
    __syncthreads();
    float a1 = 0.f, a2 = 0.f;
    int k0 = ks * 192;
    #pragma unroll 8
    for (int kk = 0; kk < 192; kk++) {
        int k = k0 + kk;
        float cv = cat[k];
        a1 += cv * p.fW1[(size_t)k * 256 + gc];
        a2 += cv * p.fW2[(size_t)k * 256 + gc];
    }
    red1[ks][c] = a1; red2[ks][c] = a2;
    __syncthreads();
    if (ks == 0) {
        float s1 = red1[0][c] + red1[1][c] + red1[2][c] + red1[3][c] + p.fb1[gc];
        float s2 = red2[0][c] + red2[1][c] + red2[2][c] + red2[3][c] + p.fb2[gc];
        float fus = fmaxf(s1, 0.f);
        float Gf = 1.f / (1.f + __expf(-s2));
        float u = Gf * fus + (1.f - Gf) * cat[gc];
        out[((size_t)(b * 16 + t)) * 512 + (size_t)blockIdx.z * 256 + gc] = u;
    }
}

extern "C" void kernel_launch(void* const* d_in, const int* in_sizes, int n_in,
                              void* d_out, int out_size, void* d_ws, size_t ws_size,
                              hipStream_t stream)
{
    const float* x = (const float*)d_in[0];
    char* base = (char*)d_ws;
    auto alloc = [&](size_t bytes){ void* r = base; base += (bytes + 255) & ~255ULL; return r; };
    short* inH = (short*)alloc(2 * 1048576 * 2);
    short* inL = (short*)alloc(2 * 1048576 * 2);
    short* hH  = (short*)alloc(2 * 1048576 * 2);
    short* hL  = (short*)alloc(2 * 1048576 * 2);
    short* t1  = (short*)alloc(2 * 1048576 * 2);
    short* wtH = (short*)alloc(10 * 65536 * 2);
    short* wtL = (short*)alloc(10 * 65536 * 2);
    float* v   = (float*)alloc(2 * 16384 * 4);
    float* vW1 = (float*)alloc(2 * 16384 * 4);
    float* vW2 = (float*)alloc(2 * 16384 * 4);
    float* E0  = (float*)alloc(2 * 1024 * 4);

    SrcPack sp;
    const int src_idx[5] = {0, 2, 3, 5, 7};  // fcW, mW1, mW2, s2tW1, s2tW
    for (int p = 0; p < 2; p++)
        for (int i = 0; i < 5; i++)
            sp.s[p * 5 + i] = (const float*)d_in[1 + p * 16 + src_idx[i]];
    transpose_k<<<dim3(16, 10), 256, 0, stream>>>(sp, wtH, wtL);

    GDir fc[2], s2t1[2];
    MbloDir mbd[2];
    PoolDir pld[2];
    G2Dir g2d[2];
    GateDir gtd[2];
    FuseDir fsd[2];
    for (int p = 0; p < 2; p++) {
        int bi = 1 + p * 16;
        const float* fcb   = (const float*)d_in[bi + 1];
        const float* mb    = (const float*)d_in[bi + 4];
        const float* s2tb1 = (const float*)d_in[bi + 6];
        const float* s2tb  = (const float*)d_in[bi + 8];
        size_t po = (size_t)p * 1048576;
        const short* W0h = wtH + (size_t)(p * 5 + 0) * 65536, *W0l = wtL + (size_t)(p * 5 + 0) * 65536;
        const short* W1h = wtH + (size_t)(p * 5 + 1) * 65536, *W1l = wtL + (size_t)(p * 5 + 1) * 65536;
        const short* W2h = wtH + (size_t)(p * 5 + 2) * 65536, *W2l = wtL + (size_t)(p * 5 + 2) * 65536;
        const short* W3h = wtH + (size_t)(p * 5 + 3) * 65536, *W3l = wtL + (size_t)(p * 5 + 3) * 65536;
        const short* W4h = wtH + (size_t)(p * 5 + 4) * 65536, *W4l = wtL + (size_t)(p * 5 + 4) * 65536;

        fc[p]   = { x, nullptr, W0h, W0l, fcb, inH + po, inL + po };
        mbd[p]  = { inH + po, inL + po, W1h, W1l, W2h, W2l, mb, hH + po, hL + po, (p == 0) };
        s2t1[p] = { hH + po, hL + po, W3h, W3l, s2tb1, t1 + po, nullptr };
        pld[p]  = { t1 + po, W4h, W4l, s2tb, hH + po, hL + po, v + p * 16384 };
        g2d[p]  = { v + p * 16384, W1h, W1l, W2h, W2l, mb, vW1 + p * 16384, vW2 + p * 16384 };
        gtd[p]  = { vW1 + p * 16384, vW2 + p * 16384, v + p * 16384,
                    (const float*)d_in[bi + 9], (const float*)d_in[bi + 10],
                    (const float*)d_in[bi + 11], E0 + p * 1024, (p == 0) };
        fsd[p]  = { inH + po, inL + po, hH + po, hL + po, E0 + p * 1024,
                    (const float*)d_in[bi + 12], (const float*)d_in[bi + 13],
                    (const float*)d_in[bi + 14], (const float*)d_in[bi + 15] };
    }

    gemm_k<1, 2, 1><<<dim3(64, 4, 2), 256, 0, stream>>>(fc[0], fc[1]);
    mblo_k<<<dim3(64, 4, 2), 256, 0, stream>>>(mbd[0], mbd[1]);
    gemm_k<2, 1, 1><<<dim3(64, 4, 2), 256, 0, stream>>>(s2t1[0], s2t1[1]);
    s2t_pool_k<<<dim3(64, 4, 2), 256, 0, stream>>>(pld[0], pld[1]);
    gemm2s_k<<<dim3(1, 8, 2), 256, 0, stream>>>(g2d[0], g2d[1]);
    attn2gate_k<<<dim3(4, 4, 2), 256, 0, stream>>>(gtd[0], gtd[1]);
    fusion_k<<<dim3(64, 4, 2), 256, 0, stream>>>(fsd[0], fsd[1], (float*)d_out);
}

// Round 7
// 211.937 us; speedup vs baseline: 5.2222x; 1.0652x over previous
//
#include <hip/hip_runtime.h>
#include <hip/hip_bf16.h>

typedef __hip_bfloat16 BF16;
typedef __attribute__((ext_vector_type(8))) short short8;
typedef __attribute__((ext_vector_type(4))) float f32x4;

#define MFMA_B16(a,b,c) __builtin_amdgcn_mfma_f32_16x16x32_bf16((a),(b),(c),0,0,0)

__device__ __forceinline__ short f2bs(float f){ BF16 h = __float2bfloat16(f); return *(short*)&h; }
__device__ __forceinline__ float bs2f(short s){ BF16 h = *(BF16*)&s; return __bfloat162float(h); }

// ---------- prep: transpose+split 10 f32 weight mats (256x256) to n-major bf16 hi/lo ----------
struct SrcPack { const float* s[10]; };

__global__ __launch_bounds__(256) void transpose_k(SrcPack p, short* __restrict__ Oh,
                                                   short* __restrict__ Ol)
{
    __shared__ float s[64][65];
    const float* W = p.s[blockIdx.y];
    short* oh = Oh + (size_t)blockIdx.y * 65536;
    short* ol = Ol + (size_t)blockIdx.y * 65536;
    int tr = (blockIdx.x >> 2) * 64, tc = (blockIdx.x & 3) * 64;
    #pragma unroll
    for (int i = 0; i < 16; i++) {
        int e = threadIdx.x + i * 256;
        int r = e >> 6, c = e & 63;
        s[c][r] = W[(size_t)(tr + r) * 256 + tc + c];
    }
    __syncthreads();
    #pragma unroll
    for (int i = 0; i < 16; i++) {
        int e = threadIdx.x + i * 256;
        int c2 = e >> 6, r2 = e & 63;
        float v = s[c2][r2];
        short hi = f2bs(v);
        short lo = f2bs(v - bs2f(hi));
        size_t oi = (size_t)(tc + c2) * 256 + tr + r2;
        oh[oi] = hi;
        ol[oi] = lo;
    }
}

// ---------- generic MFMA GEMM body, split-bf16 precision ----------
// AM: 0 = A single bf16 plane, 1 = A f32 split on the fly, 2 = A dual bf16 planes.
// OM: 0 = f32, 1 = bf16, 2 = dual planes.  BS: 1 = single-plane B (Wl unused).
template<int AM, int OM, int RELU, int BS>
__device__ __forceinline__ void gemm_body(const void* __restrict__ A0,
    const void* __restrict__ Alo,
    const short* __restrict__ Wh, const short* __restrict__ Wl,
    const float* __restrict__ bias, void* __restrict__ O0, void* __restrict__ O1,
    int row0, int col0)
{
    constexpr int LDK = 72;
    __shared__ short sAh[64 * LDK];
    __shared__ short sAl[(AM == 0) ? 8 : 64 * LDK];
    __shared__ short sBh[64 * LDK];
    __shared__ short sBl[BS ? 8 : 64 * LDK];
    int tid = threadIdx.x;
    int w = tid >> 6, l = tid & 63;
    int m = l & 15, q = l >> 4;
    int sr = w * 16 + m;

    f32x4 acc[4];
    #pragma unroll
    for (int cf = 0; cf < 4; cf++) acc[cf] = (f32x4)(0.f);

    for (int kh = 0; kh < 4; kh++) {
        int kbase = kh * 64;
        #pragma unroll
        for (int i = 0; i < 2; i++) {
            int kl = q * 8 + 32 * i;
            size_t gofs = (size_t)(row0 + sr) * 256 + kbase + kl;
            if (AM == 1) {
                const float* src = (const float*)A0 + gofs;
                float4 f0 = *(const float4*)src;
                float4 f1 = *(const float4*)(src + 4);
                short8 vh, vl;
                float tmp[8] = {f0.x, f0.y, f0.z, f0.w, f1.x, f1.y, f1.z, f1.w};
                #pragma unroll
                for (int j = 0; j < 8; j++) {
                    vh[j] = f2bs(tmp[j]);
                    vl[j] = f2bs(tmp[j] - bs2f(vh[j]));
                }
                *(short8*)&sAh[sr * LDK + kl] = vh;
                *(short8*)&sAl[sr * LDK + kl] = vl;
            } else if (AM == 2) {
                *(short8*)&sAh[sr * LDK + kl] = *(const short8*)((const short*)A0 + gofs);
                *(short8*)&sAl[sr * LDK + kl] = *(const short8*)((const short*)Alo + gofs);
            } else {
                *(short8*)&sAh[sr * LDK + kl] = *(const short8*)((const short*)A0 + gofs);
            }
            size_t gofsB = (size_t)(col0 + sr) * 256 + kbase + kl;
            *(short8*)&sBh[sr * LDK + kl] = *(const short8*)(Wh + gofsB);
            if (!BS)
                *(short8*)&sBl[sr * LDK + kl] = *(const short8*)(Wl + gofsB);
        }
        __syncthreads();
        #pragma unroll
        for (int ch = 0; ch < 2; ch++) {
            int k = ch * 32 + q * 8;
            short8 ah = *(const short8*)&sAh[(w * 16 + m) * LDK + k];
            short8 al = (AM != 0) ? *(const short8*)&sAl[(w * 16 + m) * LDK + k] : ah;
            #pragma unroll
            for (int cf = 0; cf < 4; cf++) {
                short8 bh = *(const short8*)&sBh[(cf * 16 + m) * LDK + k];
                acc[cf] = MFMA_B16(ah, bh, acc[cf]);
                if (!BS) {
                    short8 bl = *(const short8*)&sBl[(cf * 16 + m) * LDK + k];
                    acc[cf] = MFMA_B16(ah, bl, acc[cf]);
                }
                if (AM != 0)
                    acc[cf] = MFMA_B16(al, bh, acc[cf]);
            }
        }
        __syncthreads();
    }
    // C/D layout: col = lane&15, row = (lane>>4)*4 + reg (m89-verified)
    #pragma unroll
    for (int cf = 0; cf < 4; cf++) {
        int col = col0 + cf * 16 + m;
        float bv = bias ? bias[col] : 0.f;
        #pragma unroll
        for (int r = 0; r < 4; r++) {
            int row = row0 + w * 16 + q * 4 + r;
            float v = acc[cf][r] + bv;
            if (RELU) v = fmaxf(v, 0.f);
            size_t oi = (size_t)row * 256 + col;
            if (OM == 0) {
                ((float*)O0)[oi] = v;
            } else if (OM == 1) {
                ((short*)O0)[oi] = f2bs(v);
            } else {
                short hi = f2bs(v);
                ((short*)O0)[oi] = hi;
                ((short*)O1)[oi] = f2bs(v - bs2f(hi));
            }
        }
    }
}

// batched-direction generic GEMM
struct GDir { const void* A0; const void* Al; const short* Wh; const short* Wl;
              const float* bias; void* O0; void* O1; };

template<int AM, int OM, int RELU, int BS>
__global__ __launch_bounds__(256) void gemm_k(GDir p0, GDir p1)
{
    GDir p = blockIdx.z ? p1 : p0;
    gemm_body<AM, OM, RELU, BS>(p.A0, p.Al, p.Wh, p.Wl, p.bias, p.O0, p.O1,
                                blockIdx.x * 64, blockIdx.y * 64);
}

// small dual GEMM (M=64): vW1 = v@mW1, vW2 = v@mW2+mb; grid (1, 8, 2)
struct G2Dir { const float* A; const short* W1h; const short* W1l;
               const short* W2h; const short* W2l; const float* b2;
               float* C1; float* C2; };

__global__ __launch_bounds__(256) void gemm2s_k(G2Dir p0, G2Dir p1)
{
    G2Dir p = blockIdx.z ? p1 : p0;
    int y = blockIdx.y;
    const short* Wh = (y < 4) ? p.W1h : p.W2h;
    const short* Wl = (y < 4) ? p.W1l : p.W2l;
    void* C = (y < 4) ? (void*)p.C1 : (void*)p.C2;
    const float* bias = (y < 4) ? nullptr : p.b2;
    gemm_body<1, 0, 0, 0>(p.A, nullptr, Wh, Wl, bias, C, nullptr, 0, (y & 3) * 64);
}

// ---------- fused dual mSA-GEMM + level-1 masked attention, 512 threads ----------
// Block (bn, dchunk, dir): A1 = in@mW1, A2 = in@mW2+mb on its 64x64 tile (single-
// plane weights, dual-plane A), P/Q = exp(0.4*logit) into LDS, X tile, masked
// online softmax, dual-plane h out.  w_ij = e^5 * exp(-10/(1+P_i*Q_j)); e^5 cancels.
// GEMM: 8 waves = 4 row-strips x 2 col-halves. Attention: wave w rows {w, w+8, ...}.
struct MbloDir { const short* Ah; const short* Al;
                 const short* W1h; const short* W2h;
                 const float* mb; short* Hh; short* Hl; int fw; };

__global__ __launch_bounds__(512) void mblo_k(MbloDir p0, MbloDir p1)
{
    __shared__ char smraw[49152] __attribute__((aligned(16)));
    short* gAh  = (short*)smraw;            // 64*72 shorts
    short* gAl  = gAh + 4608;
    short* gB1h = gAh + 9216;
    short* gB2h = gAh + 13824;
    float* aP = (float*)smraw;              // 64*64 f32 (overlay, stride 64: 2-way free)
    float* aQ = aP + 4096;
    float* aX = aP + 8192;

    MbloDir p = blockIdx.z ? p1 : p0;
    int tid = threadIdx.x;
    int w = tid >> 6, l = tid & 63;
    int m = l & 15, q = l >> 4;
    int rh = w >> 1;            // row strip 0..3
    int cb = (w & 1) * 2;       // col-frag base: 0 or 2
    int row0 = blockIdx.x * 64, d0 = blockIdx.y * 64;
    int srow = tid >> 3;        // staging row 0..63
    int skl  = (tid & 7) * 8;   // staging k offset

    f32x4 acc1[2], acc2[2];
    #pragma unroll
    for (int cf = 0; cf < 2; cf++) { acc1[cf] = (f32x4)(0.f); acc2[cf] = (f32x4)(0.f); }

    for (int kh = 0; kh < 4; kh++) {
        int kbase = kh * 64;
        size_t ga = (size_t)(row0 + srow) * 256 + kbase + skl;
        *(short8*)&gAh[srow * 72 + skl] = *(const short8*)(p.Ah + ga);
        *(short8*)&gAl[srow * 72 + skl] = *(const short8*)(p.Al + ga);
        size_t gb = (size_t)(d0 + srow) * 256 + kbase + skl;
        *(short8*)&gB1h[srow * 72 + skl] = *(const short8*)(p.W1h + gb);
        *(short8*)&gB2h[srow * 72 + skl] = *(const short8*)(p.W2h + gb);
        __syncthreads();
        #pragma unroll
        for (int ch = 0; ch < 2; ch++) {
            int k = ch * 32 + q * 8;
            short8 ah = *(const short8*)&gAh[(rh * 16 + m) * 72 + k];
            short8 al = *(const short8*)&gAl[(rh * 16 + m) * 72 + k];
            #pragma unroll
            for (int cf = 0; cf < 2; cf++) {
                int bofs = ((cb + cf) * 16 + m) * 72 + k;
                short8 b1 = *(const short8*)&gB1h[bofs];
                acc1[cf] = MFMA_B16(ah, b1, acc1[cf]);
                acc1[cf] = MFMA_B16(al, b1, acc1[cf]);
                short8 b2 = *(const short8*)&gB2h[bofs];
                acc2[cf] = MFMA_B16(ah, b2, acc2[cf]);
                acc2[cf] = MFMA_B16(al, b2, acc2[cf]);
            }
        }
        __syncthreads();   // also guards the union overwrite below
    }
    // epilogue: P/Q into LDS (overlays staging; all reads drained by barrier)
    #pragma unroll
    for (int cf = 0; cf < 2; cf++) {
        int col = (cb + cf) * 16 + m;
        float mbv = p.mb[d0 + col];
        #pragma unroll
        for (int r = 0; r < 4; r++) {
            int row = rh * 16 + q * 4 + r;
            aP[row * 64 + col] = __expf(0.4f * acc1[cf][r]);
            aQ[row * 64 + col] = __expf(0.4f * (acc2[cf][r] + mbv));
        }
    }
    {   // X tile: one short8 pair per thread (512 x 8 = 4096 elems)
        size_t gx = (size_t)(row0 + srow) * 256 + d0 + skl;
        short8 xh = *(const short8*)(p.Ah + gx);
        short8 xl = *(const short8*)(p.Al + gx);
        #pragma unroll
        for (int t = 0; t < 8; t++)
            aX[srow * 64 + skl + t] = bs2f(xh[t]) + bs2f(xl[t]);
    }
    __syncthreads();
    // masked attention: wave w handles rows {w, w+8, ..., w+56}
    #pragma unroll
    for (int t = 0; t < 8; t++) {
        int i = w + 8 * t;
        float P = aP[i * 64 + l];
        int js = p.fw ? (i + 1) : 0;
        int je = p.fw ? 64 : i;
        float den = 0.f, num = 0.f;
        for (int j = js; j < je; j++) {
            float u = P * aQ[j * 64 + l];
            float r = __builtin_amdgcn_rcpf(1.f + u);
            float wgt = __expf(-10.f * r);
            den += wgt;
            num += wgt * aX[j * 64 + l];
        }
        float out = (je > js) ? (num * __builtin_amdgcn_rcpf(den)) : 0.f;
        short hi = f2bs(out);
        size_t oi = (size_t)(row0 + i) * 256 + d0 + l;
        p.Hh[oi] = hi;
        p.Hl[oi] = f2bs(out - bs2f(hi));
    }
}

// ---------- fused s2t logits GEMM + softmax pool ----------
struct PoolDir { const short* T1; const short* Wh; const short* Wl; const float* bias;
                 const short* Hh; const short* Hl; float* V; };

__global__ __launch_bounds__(256) void s2t_pool_k(PoolDir p0, PoolDir p1)
{
    __shared__ char smraw[37888] __attribute__((aligned(16)));
    short* gAh = (short*)smraw;             // 64*72
    short* gBh = gAh + 4608;
    short* gBl = gAh + 9216;
    float* aL = (float*)smraw;              // 64*68
    float* aH = aL + 4352;
    float* rm = aL + 8704;                  // 4*64
    float* rd = aL + 8960;
    float* rn = aL + 9216;

    PoolDir p = blockIdx.z ? p1 : p0;
    int tid = threadIdx.x;
    int w = tid >> 6, l = tid & 63;
    int m = l & 15, q = l >> 4;
    int sr = w * 16 + m;
    int row0 = blockIdx.x * 64, d0 = blockIdx.y * 64;

    f32x4 acc[4];
    #pragma unroll
    for (int cf = 0; cf < 4; cf++) acc[cf] = (f32x4)(0.f);

    for (int kh = 0; kh < 4; kh++) {
        int kbase = kh * 64;
        #pragma unroll
        for (int i = 0; i < 2; i++) {
            int kl = q * 8 + 32 * i;
            *(short8*)&gAh[sr * 72 + kl] =
                *(const short8*)(p.T1 + (size_t)(row0 + sr) * 256 + kbase + kl);
            size_t gb = (size_t)(d0 + sr) * 256 + kbase + kl;
            *(short8*)&gBh[sr * 72 + kl] = *(const short8*)(p.Wh + gb);
            *(short8*)&gBl[sr * 72 + kl] = *(const short8*)(p.Wl + gb);
        }
        __syncthreads();
        #pragma unroll
        for (int ch = 0; ch < 2; ch++) {
            int k = ch * 32 + q * 8;
            short8 ah = *(const short8*)&gAh[(w * 16 + m) * 72 + k];
            #pragma unroll
            for (int cf = 0; cf < 4; cf++) {
                int bofs = (cf * 16 + m) * 72 + k;
                short8 bh = *(const short8*)&gBh[bofs];
                short8 bl = *(const short8*)&gBl[bofs];
                acc[cf] = MFMA_B16(ah, bh, acc[cf]);
                acc[cf] = MFMA_B16(ah, bl, acc[cf]);
            }
        }
        __syncthreads();
    }
    #pragma unroll
    for (int cf = 0; cf < 4; cf++) {
        int col = cf * 16 + m;
        float bv = p.bias[d0 + col];
        #pragma unroll
        for (int r = 0; r < 4; r++) {
            int row = w * 16 + q * 4 + r;
            aL[row * 68 + col] = acc[cf][r] + bv;
        }
    }
    #pragma unroll
    for (int it = 0; it < 2; it++) {
        int e = tid + it * 256;
        int j = e >> 3, d8 = (e & 7) * 8;
        short8 xh = *(const short8*)(p.Hh + (size_t)(row0 + j) * 256 + d0 + d8);
        short8 xl = *(const short8*)(p.Hl + (size_t)(row0 + j) * 256 + d0 + d8);
        #pragma unroll
        for (int t = 0; t < 8; t++)
            aH[j * 68 + d8 + t] = bs2f(xh[t]) + bs2f(xl[t]);
    }
    __syncthreads();
    int dl = tid & 63, rq = tid >> 6;
    float mx = -1e30f, den = 0.f, num = 0.f;
    #pragma unroll
    for (int rr = 0; rr < 16; rr++) {
        int r = rq * 16 + rr;
        float lv = aL[r * 68 + dl];
        float hv = aH[r * 68 + dl];
        if (lv > mx) {
            float sc = __expf(mx - lv);
            den *= sc; num *= sc; mx = lv;
        }
        float wgt = __expf(lv - mx);
        den += wgt; num += wgt * hv;
    }
    rm[rq * 64 + dl] = mx; rd[rq * 64 + dl] = den; rn[rq * 64 + dl] = num;
    __syncthreads();
    if (rq == 0) {
        float M = fmaxf(fmaxf(rm[dl], rm[64 + dl]), fmaxf(rm[128 + dl], rm[192 + dl]));
        float D = 0.f, Nn = 0.f;
        #pragma unroll
        for (int k = 0; k < 4; k++) {
            float sc = __expf(rm[k * 64 + dl] - M);
            D += rd[k * 64 + dl] * sc;
            Nn += rn[k * 64 + dl] * sc;
        }
        p.V[(size_t)blockIdx.x * 256 + d0 + dl] = Nn / D;
    }
}

// ---------- fused level-2 attention (row 0) + gate ----------
struct GateDir { const float* vW1; const float* vW2; const float* V;
                 const float* gW1; const float* gW2; const float* gb;
                 float* E0; int fw; };

__global__ __launch_bounds__(256) void attn2gate_k(GateDir p0, GateDir p1)
{
    GateDir p = blockIdx.z ? p1 : p0;
    __shared__ float so[256], sv[256], red[4][64];
    int b = blockIdx.x, k = threadIdx.x;
    float o = 0.f;
    if (p.fw) {
        float qv = p.vW1[(size_t)(b * 16) * 256 + k];
        float den = 0.f, num = 0.f;
        for (int j = 1; j < 16; j++) {
            float z = (qv + p.vW2[(size_t)(b * 16 + j) * 256 + k]) * 0.2f;
            float e2 = __expf(2.f * z);
            float t = 1.f - 2.f / (e2 + 1.f);
            float wgt = __expf(5.f * t);
            den += wgt; num += wgt * p.V[(size_t)(b * 16 + j) * 256 + k];
        }
        o = num / den;
    }
    so[k] = o;
    sv[k] = p.V[(size_t)(b * 16) * 256 + k];
    __syncthreads();
    int c = k & 63, ks = k >> 6;
    int gc = blockIdx.y * 64 + c;
    float acc = 0.f;
    int k0 = ks * 64;
    #pragma unroll 8
    for (int kk = 0; kk < 64; kk++) {
        int kx = k0 + kk;
        acc += so[kx] * p.gW1[(size_t)kx * 256 + gc] + sv[kx] * p.gW2[(size_t)kx * 256 + gc];
    }
    red[ks][c] = acc;
    __syncthreads();
    if (ks == 0) {
        float a = red[0][c] + red[1][c] + red[2][c] + red[3][c] + p.gb[gc];
        float G = 1.f / (1.f + __expf(-a));
        p.E0[b * 256 + gc] = G * so[gc] + (1.f - G) * sv[gc];
    }
}

// ---------- fusion: grid (64 bt, 4 dchunk, 2 dir), split-K(4x192) x 64-col ----------
struct FuseDir { const short* INh; const short* INl; const short* Hh; const short* Hl;
                 const float* E0; const float* fW1; const float* fb1;
                 const float* fW2; const float* fb2; };

__global__ __launch_bounds__(256) void fusion_k(FuseDir p0, FuseDir p1, float* __restrict__ out)
{
    FuseDir p = blockIdx.z ? p1 : p0;
    __shared__ float cat[768];
    __shared__ float red1[4][64], red2[4][64];
    int bt = blockIdx.x, b = bt >> 4, t = bt & 15;
    int c = threadIdx.x & 63, ks = threadIdx.x >> 6;
    int gc = blockIdx.y * 64 + c;
    size_t xrow = ((size_t)b * 1024 + t) * 256;   // (b, n=0, r=t)
    cat[threadIdx.x]       = bs2f(p.INh[xrow + threadIdx.x]) + bs2f(p.INl[xrow + threadIdx.x]);
    cat[256 + threadIdx.x] = bs2f(p.Hh[xrow + threadIdx.x]) + bs2f(p.Hl[xrow + threadIdx.x]);
    cat[512 + threadIdx.x] = p.E0[b * 256 + threadIdx.x];
    __syncthreads();
    float a1 = 0.f, a2 = 0.f;
    int k0 = ks * 192;
    #pragma unroll 8
    for (int kk = 0; kk < 192; kk++) {
        int k = k0 + kk;
        float cv = cat[k];
        a1 += cv * p.fW1[(size_t)k * 256 + gc];
        a2 += cv * p.fW2[(size_t)k * 256 + gc];
    }
    red1[ks][c] = a1; red2[ks][c] = a2;
    __syncthreads();
    if (ks == 0) {
        float s1 = red1[0][c] + red1[1][c] + red1[2][c] + red1[3][c] + p.fb1[gc];
        float s2 = red2[0][c] + red2[1][c] + red2[2][c] + red2[3][c] + p.fb2[gc];
        float fus = fmaxf(s1, 0.f);
        float Gf = 1.f / (1.f + __expf(-s2));
        float u = Gf * fus + (1.f - Gf) * cat[gc];
        out[((size_t)(b * 16 + t)) * 512 + (size_t)blockIdx.z * 256 + gc] = u;
    }
}

extern "C" void kernel_launch(void* const* d_in, const int* in_sizes, int n_in,
                              void* d_out, int out_size, void* d_ws, size_t ws_size,
                              hipStream_t stream)
{
    const float* x = (const float*)d_in[0];
    char* base = (char*)d_ws;
    auto alloc = [&](size_t bytes){ void* r = base; base += (bytes + 255) & ~255ULL; return r; };
    short* inH = (short*)alloc(2 * 1048576 * 2);
    short* inL = (short*)alloc(2 * 1048576 * 2);
    short* hH  = (short*)alloc(2 * 1048576 * 2);
    short* hL  = (short*)alloc(2 * 1048576 * 2);
    short* t1  = (short*)alloc(2 * 1048576 * 2);
    short* wtH = (short*)alloc(10 * 65536 * 2);
    short* wtL = (short*)alloc(10 * 65536 * 2);
    float* v   = (float*)alloc(2 * 16384 * 4);
    float* vW1 = (float*)alloc(2 * 16384 * 4);
    float* vW2 = (float*)alloc(2 * 16384 * 4);
    float* E0  = (float*)alloc(2 * 1024 * 4);

    SrcPack sp;
    const int src_idx[5] = {0, 2, 3, 5, 7};  // fcW, mW1, mW2, s2tW1, s2tW
    for (int p = 0; p < 2; p++)
        for (int i = 0; i < 5; i++)
            sp.s[p * 5 + i] = (const float*)d_in[1 + p * 16 + src_idx[i]];
    transpose_k<<<dim3(16, 10), 256, 0, stream>>>(sp, wtH, wtL);

    GDir fc[2], s2t1[2];
    MbloDir mbd[2];
    PoolDir pld[2];
    G2Dir g2d[2];
    GateDir gtd[2];
    FuseDir fsd[2];
    for (int p = 0; p < 2; p++) {
        int bi = 1 + p * 16;
        const float* fcb   = (const float*)d_in[bi + 1];
        const float* mb    = (const float*)d_in[bi + 4];
        const float* s2tb1 = (const float*)d_in[bi + 6];
        const float* s2tb  = (const float*)d_in[bi + 8];
        size_t po = (size_t)p * 1048576;
        const short* W0h = wtH + (size_t)(p * 5 + 0) * 65536, *W0l = wtL + (size_t)(p * 5 + 0) * 65536;
        const short* W1h = wtH + (size_t)(p * 5 + 1) * 65536, *W1l = wtL + (size_t)(p * 5 + 1) * 65536;
        const short* W2h = wtH + (size_t)(p * 5 + 2) * 65536, *W2l = wtL + (size_t)(p * 5 + 2) * 65536;
        const short* W3h = wtH + (size_t)(p * 5 + 3) * 65536;
        const short* W4h = wtH + (size_t)(p * 5 + 4) * 65536, *W4l = wtL + (size_t)(p * 5 + 4) * 65536;

        fc[p]   = { x, nullptr, W0h, W0l, fcb, inH + po, inL + po };
        mbd[p]  = { inH + po, inL + po, W1h, W2h, mb, hH + po, hL + po, (p == 0) };
        s2t1[p] = { hH + po, hL + po, W3h, nullptr, s2tb1, t1 + po, nullptr };
        pld[p]  = { t1 + po, W4h, W4l, s2tb, hH + po, hL + po, v + p * 16384 };
        g2d[p]  = { v + p * 16384, W1h, W1l, W2h, W2l, mb, vW1 + p * 16384, vW2 + p * 16384 };
        gtd[p]  = { vW1 + p * 16384, vW2 + p * 16384, v + p * 16384,
                    (const float*)d_in[bi + 9], (const float*)d_in[bi + 10],
                    (const float*)d_in[bi + 11], E0 + p * 1024, (p == 0) };
        fsd[p]  = { inH + po, inL + po, hH + po, hL + po, E0 + p * 1024,
                    (const float*)d_in[bi + 12], (const float*)d_in[bi + 13],
                    (const float*)d_in[bi + 14], (const float*)d_in[bi + 15] };
    }

    gemm_k<1, 2, 1, 0><<<dim3(64, 4, 2), 256, 0, stream>>>(fc[0], fc[1]);
    mblo_k<<<dim3(64, 4, 2), 512, 0, stream>>>(mbd[0], mbd[1]);
    gemm_k<2, 1, 1, 1><<<dim3(64, 4, 2), 256, 0, stream>>>(s2t1[0], s2t1[1]);
    s2t_pool_k<<<dim3(64, 4, 2), 256, 0, stream>>>(pld[0], pld[1]);
    gemm2s_k<<<dim3(1, 8, 2), 256, 0, stream>>>(g2d[0], g2d[1]);
    attn2gate_k<<<dim3(4, 4, 2), 256, 0, stream>>>(gtd[0], gtd[1]);
    fusion_k<<<dim3(64, 4, 2), 256, 0, stream>>>(fsd[0], fsd[1], (float*)d_out);
}